// Round 2
// baseline (10511.761 us; speedup 1.0000x reference)
//
#include <hip/hip_runtime.h>
#include <hip/hip_bf16.h>
#include <hip/hip_cooperative_groups.h>
#include <math.h>

namespace cg = cooperative_groups;

// Problem constants
#define BB      64
#define PP      196      // 14*14
#define ENCD    512
#define ADIM    512
#define DDIM    512
#define EDIM    512
#define VDIM    32000
#define MAXLEN  51
#define TSTEPS  50       // MAXLEN - 1
#define KCAT    1536     // E + ENC + D
#define GDIM    2048     // 4*D

#define GRID_PERSIST 192  // max used: 64 attn + 125 fc = 189 in P2

typedef __attribute__((ext_vector_type(8))) short bf16x8;
typedef __attribute__((ext_vector_type(4))) float f32x4;

__device__ __forceinline__ ushort f2b(float x) {
  __hip_bfloat16 h = __float2bfloat16(x);
  return *reinterpret_cast<ushort*>(&h);
}
__device__ __forceinline__ float b2f(ushort u) {
  unsigned v = ((unsigned)u) << 16;
  return __uint_as_float(v);
}

// ---------------------------------------------------------------------------
// Workspace layout (byte offsets), total ~70 MB.
#define OFF_WFCB   0ull            // 32,768,000  bf16 W_fc (32000x512 row-major)
#define OFF_WCATB  32768000ull     //  6,291,456  bf16 [W_ih|W_hh] rows (2048x1536)
#define OFF_WDGB   39059456ull     //  1,048,576  bf16 [W_dec;W_f_beta] rows (1024x512)
#define OFF_WENCB  40108032ull     //    524,288  bf16 W_enc (512x512)
#define OFF_ENCB   40632320ull     // 12,845,056  bf16 enc sorted (64x196x512)
#define OFF_EAB    53477376ull     // 12,845,056  bf16 ea (64x196x512)
#define OFF_WIHT   66322432ull     //  1,048,576  f32 W_init_h^T
#define OFF_WICT   67371008ull     //  1,048,576  f32 W_init_c^T
#define OFF_MEAN   68419584ull     //    131,072  f32 mean_enc
#define OFF_C      68550656ull     //    131,072  f32 cell state
#define OFF_HB     68681728ull     //     65,536  bf16 h state (64x512)
#define OFF_DA     68747264ull     //    131,072  f32 da (64x512)
#define OFF_GATE   68878336ull     //    131,072  f32 gate (64x512)
#define OFF_XCATB  69009408ull     //    196,608  bf16 [emb|gate*ctx|h] (64x1536)
#define OFF_ORDER  69730304ull
#define OFF_DECLEN 69730560ull

// ---------------------------------------------------------------------------
__global__ __launch_bounds__(64) void k_sort(
    const int* __restrict__ cap_len, const int* __restrict__ caps,
    float* __restrict__ out_caps, float* __restrict__ out_declen,
    float* __restrict__ out_order, int* __restrict__ order_i,
    int* __restrict__ declen_i) {
  __shared__ int lens[BB];
  __shared__ int ord[BB];
  int i = threadIdx.x;
  lens[i] = cap_len[i];
  __syncthreads();
  int li = lens[i];
  int rank = 0;
  for (int j = 0; j < BB; ++j) {
    int lj = lens[j];
    if (lj > li || (lj == li && j < i)) rank++;
  }
  ord[rank] = i;
  __syncthreads();
  int ob = ord[i];
  order_i[i] = ob;
  int dl = lens[ob] - 1;
  declen_i[i] = dl;
  out_declen[i] = (float)dl;
  out_order[i] = (float)ob;
  for (int j = 0; j < MAXLEN; ++j)
    out_caps[i * MAXLEN + j] = (float)caps[ob * MAXLEN + j];
}

// ---------------------------------------------------------------------------
__global__ __launch_bounds__(256) void k_cvt(
    const float* __restrict__ src, ushort* __restrict__ dst, int n4) {
  for (int i = blockIdx.x * 256 + threadIdx.x; i < n4; i += gridDim.x * 256) {
    float4 v = *(const float4*)(src + 4 * (size_t)i);
    ushort4 o;
    o.x = f2b(v.x); o.y = f2b(v.y); o.z = f2b(v.z); o.w = f2b(v.w);
    *(ushort4*)(dst + 4 * (size_t)i) = o;
  }
}

__global__ __launch_bounds__(384) void k_cvt_cat(
    const float* __restrict__ W_ih, const float* __restrict__ W_hh,
    ushort* __restrict__ dst) {
  int n = blockIdx.x;
  int k = threadIdx.x * 4;
  const float* src = (k < 1024) ? (W_ih + (size_t)n * 1024 + k)
                                : (W_hh + (size_t)n * 512 + (k - 1024));
  float4 v = *(const float4*)src;
  ushort4 o;
  o.x = f2b(v.x); o.y = f2b(v.y); o.z = f2b(v.z); o.w = f2b(v.w);
  *(ushort4*)(dst + (size_t)n * KCAT + k) = o;
}

__global__ __launch_bounds__(128) void k_cvt_dg(
    const float* __restrict__ W_dec, const float* __restrict__ W_fb,
    ushort* __restrict__ dst) {
  int n = blockIdx.x;
  int k = threadIdx.x * 4;
  const float* src = (n < 512) ? (W_dec + (size_t)n * 512 + k)
                               : (W_fb + (size_t)(n - 512) * 512 + k);
  float4 v = *(const float4*)src;
  ushort4 o;
  o.x = f2b(v.x); o.y = f2b(v.y); o.z = f2b(v.z); o.w = f2b(v.w);
  *(ushort4*)(dst + (size_t)n * 512 + k) = o;
}

__global__ __launch_bounds__(256) void k_encb(
    const float* __restrict__ enc, const int* __restrict__ order_i,
    ushort* __restrict__ encb) {
  int b = blockIdx.y;
  int ob = order_i[b];
  int off = blockIdx.x * 1024 + threadIdx.x * 4;
  float4 v = *(const float4*)(enc + (size_t)ob * (PP * ENCD) + off);
  ushort4 o;
  o.x = f2b(v.x); o.y = f2b(v.y); o.z = f2b(v.z); o.w = f2b(v.w);
  *(ushort4*)(encb + (size_t)b * (PP * ENCD) + off) = o;
}

// ---------------------------------------------------------------------------
__global__ __launch_bounds__(256) void k_transpose(
    const float* __restrict__ src, int R, int C,
    float* __restrict__ dst, int dstLD) {
  __shared__ float tile[32][33];
  int tx = threadIdx.x, ty = threadIdx.y;   // 32 x 8
  int c0 = blockIdx.x * 32, r0 = blockIdx.y * 32;
  for (int i = ty; i < 32; i += 8)
    tile[i][tx] = src[(size_t)(r0 + i) * C + (c0 + tx)];
  __syncthreads();
  for (int i = ty; i < 32; i += 8)
    dst[(size_t)(c0 + i) * dstLD + (r0 + tx)] = tile[tx][i];
}

// ---------------------------------------------------------------------------
__global__ __launch_bounds__(256) void k_mean(
    const float* __restrict__ enc, const int* __restrict__ order_i,
    float* __restrict__ mean_enc) {
  int b = blockIdx.x;
  int ob = order_i[b];
  const float* src = enc + (size_t)ob * PP * ENCD;
  for (int e = threadIdx.x; e < ENCD; e += 256) {
    float acc = 0.f;
    for (int p = 0; p < PP; ++p) acc += src[p * ENCD + e];
    mean_enc[b * ENCD + e] = acc * (1.f / PP);
  }
}

// ---------------------------------------------------------------------------
__global__ __launch_bounds__(256) void k_init_hc(
    const float* __restrict__ mean_enc, const float* __restrict__ WhT,
    const float* __restrict__ bh, const float* __restrict__ WcT,
    const float* __restrict__ bc, ushort* __restrict__ hb,
    float* __restrict__ c) {
  __shared__ float m[ENCD];
  int b = blockIdx.x;
  for (int k = threadIdx.x; k < ENCD; k += 256) m[k] = mean_enc[b * ENCD + k];
  __syncthreads();
  for (int d = threadIdx.x; d < DDIM; d += 256) {
    float ah = bh[d], ac = bc[d];
    for (int k = 0; k < ENCD; ++k) {
      float mv = m[k];
      ah += mv * WhT[k * DDIM + d];
      ac += mv * WcT[k * DDIM + d];
    }
    hb[b * DDIM + d] = f2b(ah);
    c[b * DDIM + d] = ac;
  }
}

// ---------------------------------------------------------------------------
// MFMA GEMM: ea = encb @ W_enc^T + b_enc -> bf16 eab. M=12544, N=512, K=512.
__global__ __launch_bounds__(256) void k_ea_mfma(
    const ushort* __restrict__ encb, const ushort* __restrict__ Wencb,
    const float* __restrict__ b_enc, ushort* __restrict__ eab) {
  int tid = threadIdx.x, wave = tid >> 6, lane = tid & 63;
  int quad = lane >> 4, lr = lane & 15;
  int m0 = blockIdx.y * 64;
  int n0 = blockIdx.x * 128 + wave * 32;
  const ushort* Arow = encb + ((size_t)(m0 + lr)) * 512 + quad * 8;
  const ushort* B0 = Wencb + (size_t)(n0 + lr) * 512 + quad * 8;
  const ushort* B1 = B0 + 16 * 512;
  f32x4 acc[4][2] = {};
  for (int k0 = 0; k0 < 512; k0 += 32) {
    bf16x8 b0 = *reinterpret_cast<const bf16x8*>(B0 + k0);
    bf16x8 b1 = *reinterpret_cast<const bf16x8*>(B1 + k0);
#pragma unroll
    for (int mt = 0; mt < 4; ++mt) {
      bf16x8 a = *reinterpret_cast<const bf16x8*>(Arow + mt * 16 * 512 + k0);
      acc[mt][0] = __builtin_amdgcn_mfma_f32_16x16x32_bf16(a, b0, acc[mt][0], 0, 0, 0);
      acc[mt][1] = __builtin_amdgcn_mfma_f32_16x16x32_bf16(a, b1, acc[mt][1], 0, 0, 0);
    }
  }
#pragma unroll
  for (int mt = 0; mt < 4; ++mt)
#pragma unroll
    for (int nt = 0; nt < 2; ++nt) {
      int col = n0 + nt * 16 + lr;
      float bias = b_enc[col];
#pragma unroll
      for (int r = 0; r < 4; ++r) {
        int row = m0 + mt * 16 + quad * 4 + r;
        eab[(size_t)row * 512 + col] = f2b(acc[mt][nt][r] + bias);
      }
    }
}

// ---------------------------------------------------------------------------
// Args for the persistent cooperative kernel (single by-value struct).
struct DecodeArgs {
  const ushort* Wdgb;
  const float* b_dec;
  const float* b_fb;
  const ushort* eab;
  const float* w_full;
  const ushort* encb;
  const float* emb_table;
  const int* caps;
  const int* order_i;
  const int* declen_i;
  const ushort* Wcatb;
  const float* b_ih;
  const float* b_hh;
  const ushort* Wfcb;
  const float* b_fc;
  ushort* hb;
  float* c;
  float* da;
  float* gate;
  ushort* xcatb;
  float* out_alphas;
  float* out_pred;
};

// fc chunk: preds rows 0..63 x cols [chunk*256, +256) for timestep t.
__device__ void fc_chunk(int chunk, int t, const ushort* __restrict__ hb,
                         const ushort* __restrict__ Wfcb,
                         const float* __restrict__ b_fc, const int* dls,
                         float* __restrict__ out_pred, int tid) {
  int wave = tid >> 6, lane = tid & 63, quad = lane >> 4, lr = lane & 15;
  int n0 = chunk * 256 + wave * 64;
  const ushort* Arow = hb + (size_t)lr * 512 + quad * 8;
  const ushort* Bbase = Wfcb + (size_t)(n0 + lr) * 512 + quad * 8;
  f32x4 acc[4][4] = {};
  for (int k0 = 0; k0 < 512; k0 += 32) {
    bf16x8 bfr[4];
#pragma unroll
    for (int nt = 0; nt < 4; ++nt)
      bfr[nt] = *reinterpret_cast<const bf16x8*>(Bbase + (size_t)nt * 16 * 512 + k0);
#pragma unroll
    for (int mt = 0; mt < 4; ++mt) {
      bf16x8 a = *reinterpret_cast<const bf16x8*>(Arow + mt * 16 * 512 + k0);
#pragma unroll
      for (int nt = 0; nt < 4; ++nt)
        acc[mt][nt] = __builtin_amdgcn_mfma_f32_16x16x32_bf16(a, bfr[nt], acc[mt][nt], 0, 0, 0);
    }
  }
#pragma unroll
  for (int mt = 0; mt < 4; ++mt)
#pragma unroll
    for (int nt = 0; nt < 4; ++nt) {
      int col = n0 + nt * 16 + lr;
      float bias = b_fc[col];
#pragma unroll
      for (int r = 0; r < 4; ++r) {
        int row = mt * 16 + quad * 4 + r;
        int active = t < dls[row];
        out_pred[((size_t)row * TSTEPS + t) * VDIM + col] =
            active ? (acc[mt][nt][r] + bias) : 0.f;
      }
    }
}

// ---------------------------------------------------------------------------
// Persistent decode loop: GRID_PERSIST blocks x 256 threads, cooperative
// launch, 3 grid syncs per step.
//   P1: dagate (blocks 0..7)
//   P2: attention (blocks 0..63) || fc(t-1) (blocks 64..188)
//   P3: gates GEMM + fused LSTM (blocks 0..31)
__global__ __launch_bounds__(256) void k_decode_loop(DecodeArgs A) {
  cg::grid_group grid = cg::this_grid();
  __shared__ int dls[BB];
  __shared__ float wf[ADIM];
  __shared__ float das[ADIM];
  __shared__ float sc[PP];
  __shared__ float sg[4][64][16];
  int tid = threadIdx.x;
  int bid = blockIdx.x;
  int wave = tid >> 6, lane = tid & 63;
  int quad = lane >> 4, lr = lane & 15;

  if (tid < BB) dls[tid] = A.declen_i[tid];
  for (int i = tid; i < ADIM; i += 256) wf[i] = A.w_full[i];
  __syncthreads();

  for (int t = 0; t < TSTEPS; ++t) {
    // ---- P1: [da | gate] = h @ [W_dec;W_f_beta]^T (blocks 0..7) ----
    if (bid < 8) {
      int n0 = bid * 128 + wave * 32;
      const ushort* Arow = A.hb + (size_t)lr * 512 + quad * 8;
      const ushort* B0 = A.Wdgb + (size_t)(n0 + lr) * 512 + quad * 8;
      const ushort* B1 = B0 + 16 * 512;
      f32x4 acc[4][2] = {};
      for (int k0 = 0; k0 < 512; k0 += 32) {
        bf16x8 b0 = *reinterpret_cast<const bf16x8*>(B0 + k0);
        bf16x8 b1 = *reinterpret_cast<const bf16x8*>(B1 + k0);
#pragma unroll
        for (int mt = 0; mt < 4; ++mt) {
          bf16x8 a = *reinterpret_cast<const bf16x8*>(Arow + mt * 16 * 512 + k0);
          acc[mt][0] = __builtin_amdgcn_mfma_f32_16x16x32_bf16(a, b0, acc[mt][0], 0, 0, 0);
          acc[mt][1] = __builtin_amdgcn_mfma_f32_16x16x32_bf16(a, b1, acc[mt][1], 0, 0, 0);
        }
      }
#pragma unroll
      for (int mt = 0; mt < 4; ++mt)
#pragma unroll
        for (int nt = 0; nt < 2; ++nt) {
          int col = n0 + nt * 16 + lr;
#pragma unroll
          for (int r = 0; r < 4; ++r) {
            int row = mt * 16 + quad * 4 + r;
            float v = acc[mt][nt][r];
            if (col < 512) {
              A.da[row * 512 + col] = v + A.b_dec[col];
            } else {
              int cg_ = col - 512;
              A.gate[row * 512 + cg_] = 1.f / (1.f + expf(-(v + A.b_fb[cg_])));
            }
          }
        }
    }
    grid.sync();

    // ---- P2: attention (blocks 0..63) || fc(t-1) (blocks 64..188) ----
    if (bid < 64) {
      int b = bid;
      for (int i = tid; i < ADIM; i += 256) das[i] = A.da[b * ADIM + i];
      int tok = A.caps[A.order_i[b] * MAXLEN + t];
      for (int j = tid; j < 512; j += 256) {
        A.xcatb[(size_t)b * KCAT + j] = f2b(A.emb_table[(size_t)tok * EDIM + j]);
        A.xcatb[(size_t)b * KCAT + 1024 + j] = A.hb[b * 512 + j];
      }
      __syncthreads();
      for (int p = wave; p < PP; p += 4) {
        const ushort* ep = A.eab + ((size_t)b * PP + p) * ADIM + lane * 8;
        bf16x8 ev = *reinterpret_cast<const bf16x8*>(ep);
        float s = 0.f;
#pragma unroll
        for (int j = 0; j < 8; ++j) {
          int a = lane * 8 + j;
          float e = b2f((ushort)ev[j]);
          s += fmaxf(e + das[a], 0.f) * wf[a];
        }
#pragma unroll
        for (int off = 32; off; off >>= 1) s += __shfl_xor(s, off);
        if (lane == 0) sc[p] = s;
      }
      __syncthreads();
      if (wave == 0) {  // softmax over 196
        float m = -1e30f;
        for (int p = lane; p < PP; p += 64) m = fmaxf(m, sc[p]);
#pragma unroll
        for (int off = 32; off; off >>= 1) m = fmaxf(m, __shfl_xor(m, off));
        float ssum = 0.f;
        for (int p = lane; p < PP; p += 64) {
          float e = expf(sc[p] - m);
          sc[p] = e;
          ssum += e;
        }
#pragma unroll
        for (int off = 32; off; off >>= 1) ssum += __shfl_xor(ssum, off);
        float inv = 1.f / ssum;
        for (int p = lane; p < PP; p += 64) sc[p] *= inv;
      }
      __syncthreads();
      int active = t < dls[b];
      for (int p = tid; p < PP; p += 256)
        A.out_alphas[((size_t)b * TSTEPS + t) * PP + p] = active ? sc[p] : 0.f;
      int e0 = tid * 2;
      float cx = 0.f, cy = 0.f;
      const ushort* eb = A.encb + (size_t)b * (PP * ENCD) + e0;
      for (int p = 0; p < PP; ++p) {
        float a = sc[p];
        ushort2 uv = *(const ushort2*)(eb + (size_t)p * ENCD);
        cx += a * b2f(uv.x);
        cy += a * b2f(uv.y);
      }
      cx *= A.gate[b * ENCD + e0];
      cy *= A.gate[b * ENCD + e0 + 1];
      A.xcatb[(size_t)b * KCAT + 512 + e0] = f2b(cx);
      A.xcatb[(size_t)b * KCAT + 512 + e0 + 1] = f2b(cy);
    } else if (t > 0 && bid < 64 + 125) {
      fc_chunk(bid - 64, t - 1, A.hb, A.Wfcb, A.b_fc, dls, A.out_pred, tid);
    }
    grid.sync();

    // ---- P3: gates GEMM + fused LSTM (blocks 0..31) ----
    if (bid < 32) {
      int d0 = bid * 16;
      int colbase = wave * 512 + d0;  // wave w -> gate w
      const ushort* Arow = A.xcatb + (size_t)lr * KCAT + quad * 8;
      const ushort* Bp = A.Wcatb + (size_t)(colbase + lr) * KCAT + quad * 8;
      f32x4 acc[4] = {};
      for (int k0 = 0; k0 < KCAT; k0 += 32) {
        bf16x8 bfr = *reinterpret_cast<const bf16x8*>(Bp + k0);
#pragma unroll
        for (int mt = 0; mt < 4; ++mt) {
          bf16x8 a = *reinterpret_cast<const bf16x8*>(Arow + mt * 16 * KCAT + k0);
          acc[mt] = __builtin_amdgcn_mfma_f32_16x16x32_bf16(a, bfr, acc[mt], 0, 0, 0);
        }
      }
#pragma unroll
      for (int mt = 0; mt < 4; ++mt)
#pragma unroll
        for (int r = 0; r < 4; ++r)
          sg[wave][mt * 16 + quad * 4 + r][lr] = acc[mt][r];
      __syncthreads();
      for (int i = tid; i < 64 * 16; i += 256) {
        int row = i >> 4, dd = i & 15;
        int d = d0 + dd;
        float gi = sg[0][row][dd] + A.b_ih[d] + A.b_hh[d];
        float gf = sg[1][row][dd] + A.b_ih[512 + d] + A.b_hh[512 + d];
        float gg = sg[2][row][dd] + A.b_ih[1024 + d] + A.b_hh[1024 + d];
        float go = sg[3][row][dd] + A.b_ih[1536 + d] + A.b_hh[1536 + d];
        float si = 1.f / (1.f + expf(-gi));
        float sf = 1.f / (1.f + expf(-gf));
        float so = 1.f / (1.f + expf(-go));
        float cn = sf * A.c[row * DDIM + d] + si * tanhf(gg);
        float hn = so * tanhf(cn);
        A.c[row * DDIM + d] = cn;
        A.hb[row * DDIM + d] = f2b(hn);
      }
    }
    grid.sync();
  }

  // final fc for t = TSTEPS-1
  if (bid < 125) fc_chunk(bid, TSTEPS - 1, A.hb, A.Wfcb, A.b_fc, dls, A.out_pred, tid);
}

// ---------------------------------------------------------------------------
extern "C" void kernel_launch(void* const* d_in, const int* in_sizes, int n_in,
                              void* d_out, int out_size, void* d_ws,
                              size_t ws_size, hipStream_t stream) {
  const float* encoder_out = (const float*)d_in[0];
  const int* encoded_captions = (const int*)d_in[1];
  const int* cap_len = (const int*)d_in[2];
  const float* W_enc = (const float*)d_in[3];
  const float* b_enc = (const float*)d_in[4];
  const float* W_dec = (const float*)d_in[5];
  const float* b_dec = (const float*)d_in[6];
  const float* w_full = (const float*)d_in[7];
  // d_in[8] = b_full (scalar; softmax-invariant, omitted)
  const float* emb_table = (const float*)d_in[9];
  const float* W_ih = (const float*)d_in[10];
  const float* W_hh = (const float*)d_in[11];
  const float* b_ih = (const float*)d_in[12];
  const float* b_hh = (const float*)d_in[13];
  const float* W_init_h = (const float*)d_in[14];
  const float* b_init_h = (const float*)d_in[15];
  const float* W_init_c = (const float*)d_in[16];
  const float* b_init_c = (const float*)d_in[17];
  const float* W_f_beta = (const float*)d_in[18];
  const float* b_f_beta = (const float*)d_in[19];
  const float* W_fc = (const float*)d_in[20];
  const float* b_fc = (const float*)d_in[21];

  float* out = (float*)d_out;
  float* out_pred = out;
  float* out_caps = out_pred + (size_t)BB * TSTEPS * VDIM;
  float* out_declen = out_caps + BB * MAXLEN;
  float* out_alphas = out_declen + BB;
  float* out_order = out_alphas + (size_t)BB * TSTEPS * PP;

  char* base = (char*)d_ws;
  ushort* Wfcb = (ushort*)(base + OFF_WFCB);
  ushort* Wcatb = (ushort*)(base + OFF_WCATB);
  ushort* Wdgb = (ushort*)(base + OFF_WDGB);
  ushort* Wencb = (ushort*)(base + OFF_WENCB);
  ushort* encb = (ushort*)(base + OFF_ENCB);
  ushort* eab = (ushort*)(base + OFF_EAB);
  float* WihT = (float*)(base + OFF_WIHT);
  float* WicT = (float*)(base + OFF_WICT);
  float* meanb = (float*)(base + OFF_MEAN);
  float* c = (float*)(base + OFF_C);
  ushort* hb = (ushort*)(base + OFF_HB);
  float* da = (float*)(base + OFF_DA);
  float* gate = (float*)(base + OFF_GATE);
  ushort* xcatb = (ushort*)(base + OFF_XCATB);
  int* order_i = (int*)(base + OFF_ORDER);
  int* declen_i = (int*)(base + OFF_DECLEN);

  dim3 tb(32, 8);
  k_sort<<<1, 64, 0, stream>>>(cap_len, encoded_captions, out_caps, out_declen,
                               out_order, order_i, declen_i);
  // weight conversions (one-time per call)
  k_cvt<<<2048, 256, 0, stream>>>(W_fc, Wfcb, 16384000 / 4);
  k_cvt<<<64, 256, 0, stream>>>(W_enc, Wencb, 262144 / 4);
  k_cvt_cat<<<2048, 384, 0, stream>>>(W_ih, W_hh, Wcatb);
  k_cvt_dg<<<1024, 128, 0, stream>>>(W_dec, W_f_beta, Wdgb);
  k_encb<<<dim3(98, 64), 256, 0, stream>>>(encoder_out, order_i, encb);
  k_transpose<<<dim3(16, 16), tb, 0, stream>>>(W_init_h, 512, 512, WihT, 512);
  k_transpose<<<dim3(16, 16), tb, 0, stream>>>(W_init_c, 512, 512, WicT, 512);
  // prologue compute
  k_mean<<<64, 256, 0, stream>>>(encoder_out, order_i, meanb);
  k_init_hc<<<64, 256, 0, stream>>>(meanb, WihT, b_init_h, WicT, b_init_c, hb, c);
  k_ea_mfma<<<dim3(4, 196), 256, 0, stream>>>(encb, Wencb, b_enc, eab);

  // persistent decode loop: cooperative launch guarantees co-residency
  // (192 blocks x 256 thr, ~21.5 KB LDS -> well under 1 block/CU needed)
  DecodeArgs hargs;
  hargs.Wdgb = Wdgb; hargs.b_dec = b_dec; hargs.b_fb = b_f_beta;
  hargs.eab = eab; hargs.w_full = w_full; hargs.encb = encb;
  hargs.emb_table = emb_table; hargs.caps = encoded_captions;
  hargs.order_i = order_i; hargs.declen_i = declen_i;
  hargs.Wcatb = Wcatb; hargs.b_ih = b_ih; hargs.b_hh = b_hh;
  hargs.Wfcb = Wfcb; hargs.b_fc = b_fc; hargs.hb = hb; hargs.c = c;
  hargs.da = da; hargs.gate = gate; hargs.xcatb = xcatb;
  hargs.out_alphas = out_alphas; hargs.out_pred = out_pred;
  void* kargs[] = { (void*)&hargs };
  hipLaunchCooperativeKernel((const void*)k_decode_loop, dim3(GRID_PERSIST),
                             dim3(256), kargs, 0, stream);
}

// Round 3
// 8670.938 us; speedup vs baseline: 1.2123x; 1.2123x over previous
//
#include <hip/hip_runtime.h>
#include <hip/hip_bf16.h>
#include <math.h>

// Problem constants
#define BB      64
#define PP      196      // 14*14
#define ENCD    512
#define ADIM    512
#define DDIM    512
#define EDIM    512
#define VDIM    32000
#define MAXLEN  51
#define TSTEPS  50       // MAXLEN - 1
#define KCAT    1536     // E + ENC + D
#define GDIM    2048     // 4*D

#define GRID_P  64       // persistent grid: max phase width (attention = 64)

typedef __attribute__((ext_vector_type(8))) short bf16x8;
typedef __attribute__((ext_vector_type(4))) float f32x4;

__device__ __forceinline__ ushort f2b(float x) {
  __hip_bfloat16 h = __float2bfloat16(x);
  return *reinterpret_cast<ushort*>(&h);
}
__device__ __forceinline__ float b2f(ushort u) {
  unsigned v = ((unsigned)u) << 16;
  return __uint_as_float(v);
}

// Cross-XCD write-through stores (sc1): visible at L3 without any cache
// maintenance. Readers use NORMAL loads of t-indexed fresh addresses
// (first-touch -> L2 miss -> L3 has the data). No acquire fences anywhere,
// so read-only weights stay L2-resident across the whole decode loop.
__device__ __forceinline__ void st_wt_f32(float* p, float v) {
  __hip_atomic_store(p, v, __ATOMIC_RELAXED, __HIP_MEMORY_SCOPE_AGENT);
}
__device__ __forceinline__ void st_wt_u16(ushort* p, ushort v) {
  __hip_atomic_store(p, v, __ATOMIC_RELAXED, __HIP_MEMORY_SCOPE_AGENT);
}

// ---------------------------------------------------------------------------
// Workspace layout (byte offsets), total ~95 MB.
#define OFF_WFCB   0ull            // 32,768,000  bf16 W_fc (32000x512)
#define OFF_WCATB  32768000ull     //  6,291,456  bf16 [W_ih|W_hh] (2048x1536)
#define OFF_WDGB   39059456ull     //  1,048,576  bf16 [W_dec;W_f_beta] (1024x512)
#define OFF_WENCB  40108032ull     //    524,288  bf16 W_enc (512x512)
#define OFF_ENCB   40632320ull     // 12,845,056  bf16 enc sorted (64x196x512)
#define OFF_EAB    53477376ull     // 12,845,056  bf16 ea (64x196x512)
#define OFF_WIHT   66322432ull     //  1,048,576  f32 W_init_h^T
#define OFF_WICT   67371008ull     //  1,048,576  f32 W_init_c^T
#define OFF_MEAN   68419584ull     //    131,072  f32 mean_enc
#define OFF_C0     68550656ull     //    131,072  f32 c0
#define OFF_HBT    68681728ull     //  3,342,336  bf16 h history [51][64][512]
#define OFF_DAG    72024064ull     // 13,107,200  f32 [50][64][1024] da|gate
#define OFF_XCT    85131264ull     //  9,830,400  bf16 [50][64][1536] xcat
#define OFF_ORDER  94961664ull
#define OFF_DECLEN 94961920ull
#define OFF_BAR    94962176ull     // barrier: cnt @ [0], flag @ [16]

// ---------------------------------------------------------------------------
__global__ __launch_bounds__(64) void k_sort(
    const int* __restrict__ cap_len, const int* __restrict__ caps,
    float* __restrict__ out_caps, float* __restrict__ out_declen,
    float* __restrict__ out_order, int* __restrict__ order_i,
    int* __restrict__ declen_i, unsigned* __restrict__ bar) {
  __shared__ int lens[BB];
  __shared__ int ord[BB];
  int i = threadIdx.x;
  bar[i] = 0u;  // zero barrier region (64 u32 covers cnt+flag)
  lens[i] = cap_len[i];
  __syncthreads();
  int li = lens[i];
  int rank = 0;
  for (int j = 0; j < BB; ++j) {
    int lj = lens[j];
    if (lj > li || (lj == li && j < i)) rank++;
  }
  ord[rank] = i;
  __syncthreads();
  int ob = ord[i];
  order_i[i] = ob;
  int dl = lens[ob] - 1;
  declen_i[i] = dl;
  out_declen[i] = (float)dl;
  out_order[i] = (float)ob;
  for (int j = 0; j < MAXLEN; ++j)
    out_caps[i * MAXLEN + j] = (float)caps[ob * MAXLEN + j];
}

// ---------------------------------------------------------------------------
__global__ __launch_bounds__(256) void k_cvt(
    const float* __restrict__ src, ushort* __restrict__ dst, int n4) {
  for (int i = blockIdx.x * 256 + threadIdx.x; i < n4; i += gridDim.x * 256) {
    float4 v = *(const float4*)(src + 4 * (size_t)i);
    ushort4 o;
    o.x = f2b(v.x); o.y = f2b(v.y); o.z = f2b(v.z); o.w = f2b(v.w);
    *(ushort4*)(dst + 4 * (size_t)i) = o;
  }
}

__global__ __launch_bounds__(384) void k_cvt_cat(
    const float* __restrict__ W_ih, const float* __restrict__ W_hh,
    ushort* __restrict__ dst) {
  int n = blockIdx.x;
  int k = threadIdx.x * 4;
  const float* src = (k < 1024) ? (W_ih + (size_t)n * 1024 + k)
                                : (W_hh + (size_t)n * 512 + (k - 1024));
  float4 v = *(const float4*)src;
  ushort4 o;
  o.x = f2b(v.x); o.y = f2b(v.y); o.z = f2b(v.z); o.w = f2b(v.w);
  *(ushort4*)(dst + (size_t)n * KCAT + k) = o;
}

__global__ __launch_bounds__(128) void k_cvt_dg(
    const float* __restrict__ W_dec, const float* __restrict__ W_fb,
    ushort* __restrict__ dst) {
  int n = blockIdx.x;
  int k = threadIdx.x * 4;
  const float* src = (n < 512) ? (W_dec + (size_t)n * 512 + k)
                               : (W_fb + (size_t)(n - 512) * 512 + k);
  float4 v = *(const float4*)src;
  ushort4 o;
  o.x = f2b(v.x); o.y = f2b(v.y); o.z = f2b(v.z); o.w = f2b(v.w);
  *(ushort4*)(dst + (size_t)n * 512 + k) = o;
}

__global__ __launch_bounds__(256) void k_encb(
    const float* __restrict__ enc, const int* __restrict__ order_i,
    ushort* __restrict__ encb) {
  int b = blockIdx.y;
  int ob = order_i[b];
  int off = blockIdx.x * 1024 + threadIdx.x * 4;
  float4 v = *(const float4*)(enc + (size_t)ob * (PP * ENCD) + off);
  ushort4 o;
  o.x = f2b(v.x); o.y = f2b(v.y); o.z = f2b(v.z); o.w = f2b(v.w);
  *(ushort4*)(encb + (size_t)b * (PP * ENCD) + off) = o;
}

// ---------------------------------------------------------------------------
__global__ __launch_bounds__(256) void k_transpose(
    const float* __restrict__ src, int R, int C,
    float* __restrict__ dst, int dstLD) {
  __shared__ float tile[32][33];
  int tx = threadIdx.x, ty = threadIdx.y;   // 32 x 8
  int c0 = blockIdx.x * 32, r0 = blockIdx.y * 32;
  for (int i = ty; i < 32; i += 8)
    tile[i][tx] = src[(size_t)(r0 + i) * C + (c0 + tx)];
  __syncthreads();
  for (int i = ty; i < 32; i += 8)
    dst[(size_t)(c0 + i) * dstLD + (r0 + tx)] = tile[tx][i];
}

// ---------------------------------------------------------------------------
__global__ __launch_bounds__(256) void k_mean(
    const float* __restrict__ enc, const int* __restrict__ order_i,
    float* __restrict__ mean_enc) {
  int b = blockIdx.x;
  int ob = order_i[b];
  const float* src = enc + (size_t)ob * PP * ENCD;
  for (int e = threadIdx.x; e < ENCD; e += 256) {
    float acc = 0.f;
    for (int p = 0; p < PP; ++p) acc += src[p * ENCD + e];
    mean_enc[b * ENCD + e] = acc * (1.f / PP);
  }
}

// ---------------------------------------------------------------------------
__global__ __launch_bounds__(256) void k_init_hc(
    const float* __restrict__ mean_enc, const float* __restrict__ WhT,
    const float* __restrict__ bh, const float* __restrict__ WcT,
    const float* __restrict__ bc, ushort* __restrict__ hbt0,
    float* __restrict__ c0) {
  __shared__ float m[ENCD];
  int b = blockIdx.x;
  for (int k = threadIdx.x; k < ENCD; k += 256) m[k] = mean_enc[b * ENCD + k];
  __syncthreads();
  for (int d = threadIdx.x; d < DDIM; d += 256) {
    float ah = bh[d], ac = bc[d];
    for (int k = 0; k < ENCD; ++k) {
      float mv = m[k];
      ah += mv * WhT[k * DDIM + d];
      ac += mv * WcT[k * DDIM + d];
    }
    hbt0[b * DDIM + d] = f2b(ah);
    c0[b * DDIM + d] = ac;
  }
}

// ---------------------------------------------------------------------------
// MFMA GEMM: ea = encb @ W_enc^T + b_enc -> bf16 eab. M=12544, N=512, K=512.
__global__ __launch_bounds__(256) void k_ea_mfma(
    const ushort* __restrict__ encb, const ushort* __restrict__ Wencb,
    const float* __restrict__ b_enc, ushort* __restrict__ eab) {
  int tid = threadIdx.x, wave = tid >> 6, lane = tid & 63;
  int quad = lane >> 4, lr = lane & 15;
  int m0 = blockIdx.y * 64;
  int n0 = blockIdx.x * 128 + wave * 32;
  const ushort* Arow = encb + ((size_t)(m0 + lr)) * 512 + quad * 8;
  const ushort* B0 = Wencb + (size_t)(n0 + lr) * 512 + quad * 8;
  const ushort* B1 = B0 + 16 * 512;
  f32x4 acc[4][2] = {};
  for (int k0 = 0; k0 < 512; k0 += 32) {
    bf16x8 b0 = *reinterpret_cast<const bf16x8*>(B0 + k0);
    bf16x8 b1 = *reinterpret_cast<const bf16x8*>(B1 + k0);
#pragma unroll
    for (int mt = 0; mt < 4; ++mt) {
      bf16x8 a = *reinterpret_cast<const bf16x8*>(Arow + mt * 16 * 512 + k0);
      acc[mt][0] = __builtin_amdgcn_mfma_f32_16x16x32_bf16(a, b0, acc[mt][0], 0, 0, 0);
      acc[mt][1] = __builtin_amdgcn_mfma_f32_16x16x32_bf16(a, b1, acc[mt][1], 0, 0, 0);
    }
  }
#pragma unroll
  for (int mt = 0; mt < 4; ++mt)
#pragma unroll
    for (int nt = 0; nt < 2; ++nt) {
      int col = n0 + nt * 16 + lr;
      float bias = b_enc[col];
#pragma unroll
      for (int r = 0; r < 4; ++r) {
        int row = m0 + mt * 16 + quad * 4 + r;
        eab[(size_t)row * 512 + col] = f2b(acc[mt][nt][r] + bias);
      }
    }
}

// ---------------------------------------------------------------------------
// Lightweight grid barrier: relaxed agent atomics only — NO cache
// invalidation, weights stay L2-resident. Monotonic counter (no reset race).
// Correctness: producer's write-through stores complete (vmcnt0) before its
// arrive; flag RMW/loads execute at L3 (agent scope, sc1).
__device__ __forceinline__ void lsync(unsigned* cnt, unsigned* flag,
                                      unsigned& gen) {
  __syncthreads();
  if (threadIdx.x == 0) {
    ++gen;
    asm volatile("s_waitcnt vmcnt(0)" ::: "memory");
    unsigned old = __hip_atomic_fetch_add(cnt, 1u, __ATOMIC_RELAXED,
                                          __HIP_MEMORY_SCOPE_AGENT);
    if (old == gen * GRID_P - 1u) {
      __hip_atomic_store(flag, gen, __ATOMIC_RELAXED,
                         __HIP_MEMORY_SCOPE_AGENT);
    } else {
      while (__hip_atomic_load(flag, __ATOMIC_RELAXED,
                               __HIP_MEMORY_SCOPE_AGENT) < gen)
        __builtin_amdgcn_s_sleep(1);
    }
  }
  __syncthreads();
}

// ---------------------------------------------------------------------------
struct DecodeArgs {
  const ushort* Wdgb;
  const float* b_dec;
  const float* b_fb;
  const ushort* eab;
  const float* w_full;
  const ushort* encb;
  const float* emb_table;
  const int* caps;
  const int* order_i;
  const int* declen_i;
  const ushort* Wcatb;
  const float* b_ih;
  const float* b_hh;
  const float* c0;
  ushort* hbt;        // [51][64][512] h history (rotating, write-through)
  float* dag;         // [50][64][1024] da|gate (rotating, write-through)
  ushort* xct;        // [50][64][1536] xcat (rotating, write-through)
  float* out_alphas;
  unsigned* cnt;
  unsigned* flag;
};

// Persistent decode loop: 64 blocks x 256 threads, cooperative launch
// (co-residency guarantee only; sync is custom lsync).
//   P1: dagate (blocks 0..7)      -> dag[t]
//   P2: attention (blocks 0..63)  -> xcat[t], alphas
//   P3: gates GEMM + LSTM (0..31) -> hbt[t+1]; c lives in registers
__global__ __launch_bounds__(256) void k_decode_loop(DecodeArgs A) {
  __shared__ int dls[BB];
  __shared__ float wf[ADIM];
  __shared__ float das[ADIM];
  __shared__ float sc[PP];
  __shared__ float sg[4][64][16];
  int tid = threadIdx.x;
  int bid = blockIdx.x;
  int wave = tid >> 6, lane = tid & 63;
  int quad = lane >> 4, lr = lane & 15;
  unsigned gen = 0;
  float creg[4];  // P3 cell state (blocks 0..31): rows tid>>4 + it*16... see use

  if (tid < BB) dls[tid] = A.declen_i[tid];
  for (int i = tid; i < ADIM; i += 256) wf[i] = A.w_full[i];
  __syncthreads();

  for (int t = 0; t < TSTEPS; ++t) {
    const ushort* hcur = A.hbt + (size_t)t * BB * DDIM;
    float* dagt = A.dag + (size_t)t * BB * 1024;
    ushort* xctt = A.xct + (size_t)t * BB * KCAT;

    // ---- P1: [da | gate] = h_t @ [W_dec;W_f_beta]^T (blocks 0..7) ----
    if (bid < 8) {
      int n0 = bid * 128 + wave * 32;
      const ushort* Arow = hcur + (size_t)lr * 512 + quad * 8;
      const ushort* B0 = A.Wdgb + (size_t)(n0 + lr) * 512 + quad * 8;
      const ushort* B1 = B0 + 16 * 512;
      f32x4 acc[4][2] = {};
      for (int k0 = 0; k0 < 512; k0 += 32) {
        bf16x8 b0 = *reinterpret_cast<const bf16x8*>(B0 + k0);
        bf16x8 b1 = *reinterpret_cast<const bf16x8*>(B1 + k0);
#pragma unroll
        for (int mt = 0; mt < 4; ++mt) {
          bf16x8 a = *reinterpret_cast<const bf16x8*>(Arow + mt * 16 * 512 + k0);
          acc[mt][0] = __builtin_amdgcn_mfma_f32_16x16x32_bf16(a, b0, acc[mt][0], 0, 0, 0);
          acc[mt][1] = __builtin_amdgcn_mfma_f32_16x16x32_bf16(a, b1, acc[mt][1], 0, 0, 0);
        }
      }
#pragma unroll
      for (int mt = 0; mt < 4; ++mt)
#pragma unroll
        for (int nt = 0; nt < 2; ++nt) {
          int col = n0 + nt * 16 + lr;
#pragma unroll
          for (int r = 0; r < 4; ++r) {
            int row = mt * 16 + quad * 4 + r;
            float v = acc[mt][nt][r];
            if (col < 512) {
              st_wt_f32(&dagt[row * 1024 + col], v + A.b_dec[col]);
            } else {
              int cg = col - 512;
              st_wt_f32(&dagt[row * 1024 + 512 + cg],
                        1.f / (1.f + expf(-(v + A.b_fb[cg]))));
            }
          }
        }
    }
    lsync(A.cnt, A.flag, gen);

    // ---- P2: attention (blocks 0..63, block b = batch b) ----
    {
      int b = bid;
      for (int i = tid; i < ADIM; i += 256) das[i] = dagt[b * 1024 + i];
      int tok = A.caps[A.order_i[b] * MAXLEN + t];
      for (int j = tid; j < 512; j += 256) {
        st_wt_u16(&xctt[(size_t)b * KCAT + j],
                  f2b(A.emb_table[(size_t)tok * EDIM + j]));
        st_wt_u16(&xctt[(size_t)b * KCAT + 1024 + j], hcur[b * 512 + j]);
      }
      __syncthreads();
      for (int p = wave; p < PP; p += 4) {
        const ushort* ep = A.eab + ((size_t)b * PP + p) * ADIM + lane * 8;
        bf16x8 ev = *reinterpret_cast<const bf16x8*>(ep);
        float s = 0.f;
#pragma unroll
        for (int j = 0; j < 8; ++j) {
          int a = lane * 8 + j;
          float e = b2f((ushort)ev[j]);
          s += fmaxf(e + das[a], 0.f) * wf[a];
        }
#pragma unroll
        for (int off = 32; off; off >>= 1) s += __shfl_xor(s, off);
        if (lane == 0) sc[p] = s;
      }
      __syncthreads();
      if (wave == 0) {  // softmax over 196
        float m = -1e30f;
        for (int p = lane; p < PP; p += 64) m = fmaxf(m, sc[p]);
#pragma unroll
        for (int off = 32; off; off >>= 1) m = fmaxf(m, __shfl_xor(m, off));
        float ssum = 0.f;
        for (int p = lane; p < PP; p += 64) {
          float e = expf(sc[p] - m);
          sc[p] = e;
          ssum += e;
        }
#pragma unroll
        for (int off = 32; off; off >>= 1) ssum += __shfl_xor(ssum, off);
        float inv = 1.f / ssum;
        for (int p = lane; p < PP; p += 64) sc[p] *= inv;
      }
      __syncthreads();
      int active = t < dls[b];
      for (int p = tid; p < PP; p += 256)
        A.out_alphas[((size_t)b * TSTEPS + t) * PP + p] = active ? sc[p] : 0.f;
      int e0 = tid * 2;
      float cx = 0.f, cy = 0.f;
      const ushort* eb = A.encb + (size_t)b * (PP * ENCD) + e0;
      for (int p = 0; p < PP; ++p) {
        float a = sc[p];
        ushort2 uv = *(const ushort2*)(eb + (size_t)p * ENCD);
        cx += a * b2f(uv.x);
        cy += a * b2f(uv.y);
      }
      cx *= dagt[b * 1024 + 512 + e0];
      cy *= dagt[b * 1024 + 512 + e0 + 1];
      st_wt_u16(&xctt[(size_t)b * KCAT + 512 + e0], f2b(cx));
      st_wt_u16(&xctt[(size_t)b * KCAT + 512 + e0 + 1], f2b(cy));
    }
    lsync(A.cnt, A.flag, gen);

    // ---- P3: gates GEMM + fused LSTM (blocks 0..31) ----
    if (bid < 32) {
      int d0 = bid * 16;
      int colbase = wave * 512 + d0;  // wave w -> gate w
      const ushort* Arow = xctt + (size_t)lr * KCAT + quad * 8;
      const ushort* Bp = A.Wcatb + (size_t)(colbase + lr) * KCAT + quad * 8;
      f32x4 acc[4] = {};
      for (int k0 = 0; k0 < KCAT; k0 += 32) {
        bf16x8 bfr = *reinterpret_cast<const bf16x8*>(Bp + k0);
#pragma unroll
        for (int mt = 0; mt < 4; ++mt) {
          bf16x8 a = *reinterpret_cast<const bf16x8*>(Arow + mt * 16 * KCAT + k0);
          acc[mt] = __builtin_amdgcn_mfma_f32_16x16x32_bf16(a, bfr, acc[mt], 0, 0, 0);
        }
      }
#pragma unroll
      for (int mt = 0; mt < 4; ++mt)
#pragma unroll
        for (int r = 0; r < 4; ++r)
          sg[wave][mt * 16 + quad * 4 + r][lr] = acc[mt][r];
      __syncthreads();
      ushort* hnext = A.hbt + (size_t)(t + 1) * BB * DDIM;
#pragma unroll
      for (int it = 0; it < 4; ++it) {
        int i = tid + it * 256;
        int row = i >> 4, dd = i & 15;
        int d = d0 + dd;
        float gi = sg[0][row][dd] + A.b_ih[d] + A.b_hh[d];
        float gf = sg[1][row][dd] + A.b_ih[512 + d] + A.b_hh[512 + d];
        float gg = sg[2][row][dd] + A.b_ih[1024 + d] + A.b_hh[1024 + d];
        float go = sg[3][row][dd] + A.b_ih[1536 + d] + A.b_hh[1536 + d];
        float si = 1.f / (1.f + expf(-gi));
        float sf = 1.f / (1.f + expf(-gf));
        float so = 1.f / (1.f + expf(-go));
        if (t == 0) creg[it] = A.c0[row * DDIM + d];
        float cn = sf * creg[it] + si * tanhf(gg);
        creg[it] = cn;
        float hn = so * tanhf(cn);
        st_wt_u16(&hnext[row * DDIM + d], f2b(hn));
      }
    }
    lsync(A.cnt, A.flag, gen);
  }
}

// ---------------------------------------------------------------------------
// Batched fc: preds[b,t,:] = h_{t+1}[b,:] @ W_fc^T + b_fc (masked).
// grid (x=t:50, y=chunk:125); consecutive blocks share the W_fc chunk.
__global__ __launch_bounds__(256) void k_fc_batch(
    const ushort* __restrict__ hbt, const ushort* __restrict__ Wfcb,
    const float* __restrict__ b_fc, const int* __restrict__ declen_i,
    float* __restrict__ out_pred) {
  __shared__ int dls[BB];
  int tid = threadIdx.x;
  int t = blockIdx.x, chunk = blockIdx.y;
  if (tid < 64) dls[tid] = declen_i[tid];
  __syncthreads();
  int wave = tid >> 6, lane = tid & 63, quad = lane >> 4, lr = lane & 15;
  int n0 = chunk * 256 + wave * 64;
  const ushort* Arow = hbt + (size_t)(t + 1) * BB * DDIM + (size_t)lr * 512 + quad * 8;
  const ushort* Bbase = Wfcb + (size_t)(n0 + lr) * 512 + quad * 8;
  f32x4 acc[4][4] = {};
  for (int k0 = 0; k0 < 512; k0 += 32) {
    bf16x8 bfr[4];
#pragma unroll
    for (int nt = 0; nt < 4; ++nt)
      bfr[nt] = *reinterpret_cast<const bf16x8*>(Bbase + (size_t)nt * 16 * 512 + k0);
#pragma unroll
    for (int mt = 0; mt < 4; ++mt) {
      bf16x8 a = *reinterpret_cast<const bf16x8*>(Arow + mt * 16 * 512 + k0);
#pragma unroll
      for (int nt = 0; nt < 4; ++nt)
        acc[mt][nt] = __builtin_amdgcn_mfma_f32_16x16x32_bf16(a, bfr[nt], acc[mt][nt], 0, 0, 0);
    }
  }
#pragma unroll
  for (int mt = 0; mt < 4; ++mt)
#pragma unroll
    for (int nt = 0; nt < 4; ++nt) {
      int col = n0 + nt * 16 + lr;
      float bias = b_fc[col];
#pragma unroll
      for (int r = 0; r < 4; ++r) {
        int row = mt * 16 + quad * 4 + r;
        int active = t < dls[row];
        out_pred[((size_t)row * TSTEPS + t) * VDIM + col] =
            active ? (acc[mt][nt][r] + bias) : 0.f;
      }
    }
}

// ---------------------------------------------------------------------------
extern "C" void kernel_launch(void* const* d_in, const int* in_sizes, int n_in,
                              void* d_out, int out_size, void* d_ws,
                              size_t ws_size, hipStream_t stream) {
  const float* encoder_out = (const float*)d_in[0];
  const int* encoded_captions = (const int*)d_in[1];
  const int* cap_len = (const int*)d_in[2];
  const float* W_enc = (const float*)d_in[3];
  const float* b_enc = (const float*)d_in[4];
  const float* W_dec = (const float*)d_in[5];
  const float* b_dec = (const float*)d_in[6];
  const float* w_full = (const float*)d_in[7];
  // d_in[8] = b_full (scalar; softmax-invariant, omitted)
  const float* emb_table = (const float*)d_in[9];
  const float* W_ih = (const float*)d_in[10];
  const float* W_hh = (const float*)d_in[11];
  const float* b_ih = (const float*)d_in[12];
  const float* b_hh = (const float*)d_in[13];
  const float* W_init_h = (const float*)d_in[14];
  const float* b_init_h = (const float*)d_in[15];
  const float* W_init_c = (const float*)d_in[16];
  const float* b_init_c = (const float*)d_in[17];
  const float* W_f_beta = (const float*)d_in[18];
  const float* b_f_beta = (const float*)d_in[19];
  const float* W_fc = (const float*)d_in[20];
  const float* b_fc = (const float*)d_in[21];

  float* out = (float*)d_out;
  float* out_pred = out;
  float* out_caps = out_pred + (size_t)BB * TSTEPS * VDIM;
  float* out_declen = out_caps + BB * MAXLEN;
  float* out_alphas = out_declen + BB;
  float* out_order = out_alphas + (size_t)BB * TSTEPS * PP;

  char* base = (char*)d_ws;
  ushort* Wfcb = (ushort*)(base + OFF_WFCB);
  ushort* Wcatb = (ushort*)(base + OFF_WCATB);
  ushort* Wdgb = (ushort*)(base + OFF_WDGB);
  ushort* Wencb = (ushort*)(base + OFF_WENCB);
  ushort* encb = (ushort*)(base + OFF_ENCB);
  ushort* eab = (ushort*)(base + OFF_EAB);
  float* WihT = (float*)(base + OFF_WIHT);
  float* WicT = (float*)(base + OFF_WICT);
  float* meanb = (float*)(base + OFF_MEAN);
  float* c0 = (float*)(base + OFF_C0);
  ushort* hbt = (ushort*)(base + OFF_HBT);
  float* dag = (float*)(base + OFF_DAG);
  ushort* xct = (ushort*)(base + OFF_XCT);
  int* order_i = (int*)(base + OFF_ORDER);
  int* declen_i = (int*)(base + OFF_DECLEN);
  unsigned* bar = (unsigned*)(base + OFF_BAR);

  dim3 tb(32, 8);
  k_sort<<<1, 64, 0, stream>>>(cap_len, encoded_captions, out_caps, out_declen,
                               out_order, order_i, declen_i, bar);
  // weight conversions (one-time per call)
  k_cvt<<<2048, 256, 0, stream>>>(W_fc, Wfcb, 16384000 / 4);
  k_cvt<<<64, 256, 0, stream>>>(W_enc, Wencb, 262144 / 4);
  k_cvt_cat<<<2048, 384, 0, stream>>>(W_ih, W_hh, Wcatb);
  k_cvt_dg<<<1024, 128, 0, stream>>>(W_dec, W_f_beta, Wdgb);
  k_encb<<<dim3(98, 64), 256, 0, stream>>>(encoder_out, order_i, encb);
  k_transpose<<<dim3(16, 16), tb, 0, stream>>>(W_init_h, 512, 512, WihT, 512);
  k_transpose<<<dim3(16, 16), tb, 0, stream>>>(W_init_c, 512, 512, WicT, 512);
  // prologue compute
  k_mean<<<64, 256, 0, stream>>>(encoder_out, order_i, meanb);
  k_init_hc<<<64, 256, 0, stream>>>(meanb, WihT, b_init_h, WicT, b_init_c,
                                    hbt, c0);
  k_ea_mfma<<<dim3(4, 196), 256, 0, stream>>>(encb, Wencb, b_enc, eab);

  // persistent decode loop (no fc inside; h history saved per step)
  DecodeArgs hargs;
  hargs.Wdgb = Wdgb; hargs.b_dec = b_dec; hargs.b_fb = b_f_beta;
  hargs.eab = eab; hargs.w_full = w_full; hargs.encb = encb;
  hargs.emb_table = emb_table; hargs.caps = encoded_captions;
  hargs.order_i = order_i; hargs.declen_i = declen_i;
  hargs.Wcatb = Wcatb; hargs.b_ih = b_ih; hargs.b_hh = b_hh;
  hargs.c0 = c0; hargs.hbt = hbt; hargs.dag = dag; hargs.xct = xct;
  hargs.out_alphas = out_alphas; hargs.cnt = bar; hargs.flag = bar + 4;
  void* kargs[] = { (void*)&hargs };
  hipLaunchCooperativeKernel((const void*)k_decode_loop, dim3(GRID_P),
                             dim3(256), kargs, 0, stream);

  // batched fc over all timesteps (write-BW bound, full-chip)
  k_fc_batch<<<dim3(TSTEPS, 125), 256, 0, stream>>>(hbt, Wfcb, b_fc, declen_i,
                                                    out_pred);
}

// Round 4
// 4032.189 us; speedup vs baseline: 2.6070x; 2.1504x over previous
//
#include <hip/hip_runtime.h>
#include <hip/hip_bf16.h>
#include <math.h>

// Problem constants
#define BB      64
#define PP      196      // 14*14
#define ENCD    512
#define ADIM    512
#define DDIM    512
#define EDIM    512
#define VDIM    32000
#define MAXLEN  51
#define TSTEPS  50       // MAXLEN - 1
#define KCAT    1536     // E + ENC + D
#define GDIM    2048     // 4*D

#define NDECODE 64        // decode blocks (barrier participants)
#define GRID_TOTAL 256    // + 192 fc blocks
#define FCTILES (TSTEPS * 125)

typedef __attribute__((ext_vector_type(8))) short bf16x8;
typedef __attribute__((ext_vector_type(4))) float f32x4;

__device__ __forceinline__ ushort f2b(float x) {
  __hip_bfloat16 h = __float2bfloat16(x);
  return *reinterpret_cast<ushort*>(&h);
}
__device__ __forceinline__ float b2f(ushort u) {
  unsigned v = ((unsigned)u) << 16;
  return __uint_as_float(v);
}

// Cross-XCD write-through stores: visible at L3 without cache maintenance.
// Readers use NORMAL loads of t-indexed fresh addresses (first touch misses
// local L2 -> L3 has the data). No acquire fences => weights stay L2-resident.
__device__ __forceinline__ void st_wt_f32(float* p, float v) {
  __hip_atomic_store(p, v, __ATOMIC_RELAXED, __HIP_MEMORY_SCOPE_AGENT);
}
__device__ __forceinline__ void st_wt_u16(ushort* p, ushort v) {
  __hip_atomic_store(p, v, __ATOMIC_RELAXED, __HIP_MEMORY_SCOPE_AGENT);
}

// ---------------------------------------------------------------------------
// Workspace layout (byte offsets), total ~95 MB.
#define OFF_WFCB   0ull            // 32,768,000  bf16 W_fc (32000x512)
#define OFF_WCATB  32768000ull     //  6,291,456  bf16 [W_ih|W_hh] (2048x1536)
#define OFF_WDGB   39059456ull     //  1,048,576  bf16 [W_dec;W_f_beta] (1024x512)
#define OFF_WENCB  40108032ull     //    524,288  bf16 W_enc (512x512)
#define OFF_ENCB   40632320ull     // 12,845,056  bf16 enc sorted (64x196x512)
#define OFF_EAB    53477376ull     // 12,845,056  bf16 ea (64x196x512)
#define OFF_WIHT   66322432ull     //  1,048,576  f32 W_init_h^T
#define OFF_WICT   67371008ull     //  1,048,576  f32 W_init_c^T
#define OFF_MEAN   68419584ull     //    131,072  f32 mean_enc
#define OFF_C0     68550656ull     //    131,072  f32 c0
#define OFF_HBT    68681728ull     //  3,342,336  bf16 h history [51][64][512]
#define OFF_DAG    72024064ull     // 13,107,200  f32 [50][64][1024] da|gate
#define OFF_XCT    85131264ull     //  9,830,400  bf16 [50][64][1536] xcat
#define OFF_ORDER  94961664ull
#define OFF_DECLEN 94961920ull
#define OFF_BAR    94962176ull     // barrier: cnt @ [0], flag @ [16]

// ---------------------------------------------------------------------------
__global__ __launch_bounds__(64) void k_sort(
    const int* __restrict__ cap_len, const int* __restrict__ caps,
    float* __restrict__ out_caps, float* __restrict__ out_declen,
    float* __restrict__ out_order, int* __restrict__ order_i,
    int* __restrict__ declen_i, unsigned* __restrict__ bar) {
  __shared__ int lens[BB];
  __shared__ int ord[BB];
  int i = threadIdx.x;
  bar[i] = 0u;  // zero barrier region (cnt @0, flag @16)
  lens[i] = cap_len[i];
  __syncthreads();
  int li = lens[i];
  int rank = 0;
  for (int j = 0; j < BB; ++j) {
    int lj = lens[j];
    if (lj > li || (lj == li && j < i)) rank++;
  }
  ord[rank] = i;
  __syncthreads();
  int ob = ord[i];
  order_i[i] = ob;
  int dl = lens[ob] - 1;
  declen_i[i] = dl;
  out_declen[i] = (float)dl;
  out_order[i] = (float)ob;
  for (int j = 0; j < MAXLEN; ++j)
    out_caps[i * MAXLEN + j] = (float)caps[ob * MAXLEN + j];
}

// ---------------------------------------------------------------------------
__global__ __launch_bounds__(256) void k_cvt(
    const float* __restrict__ src, ushort* __restrict__ dst, int n4) {
  for (int i = blockIdx.x * 256 + threadIdx.x; i < n4; i += gridDim.x * 256) {
    float4 v = *(const float4*)(src + 4 * (size_t)i);
    ushort4 o;
    o.x = f2b(v.x); o.y = f2b(v.y); o.z = f2b(v.z); o.w = f2b(v.w);
    *(ushort4*)(dst + 4 * (size_t)i) = o;
  }
}

__global__ __launch_bounds__(384) void k_cvt_cat(
    const float* __restrict__ W_ih, const float* __restrict__ W_hh,
    ushort* __restrict__ dst) {
  int n = blockIdx.x;
  int k = threadIdx.x * 4;
  const float* src = (k < 1024) ? (W_ih + (size_t)n * 1024 + k)
                                : (W_hh + (size_t)n * 512 + (k - 1024));
  float4 v = *(const float4*)src;
  ushort4 o;
  o.x = f2b(v.x); o.y = f2b(v.y); o.z = f2b(v.z); o.w = f2b(v.w);
  *(ushort4*)(dst + (size_t)n * KCAT + k) = o;
}

__global__ __launch_bounds__(128) void k_cvt_dg(
    const float* __restrict__ W_dec, const float* __restrict__ W_fb,
    ushort* __restrict__ dst) {
  int n = blockIdx.x;
  int k = threadIdx.x * 4;
  const float* src = (n < 512) ? (W_dec + (size_t)n * 512 + k)
                               : (W_fb + (size_t)(n - 512) * 512 + k);
  float4 v = *(const float4*)src;
  ushort4 o;
  o.x = f2b(v.x); o.y = f2b(v.y); o.z = f2b(v.z); o.w = f2b(v.w);
  *(ushort4*)(dst + (size_t)n * 512 + k) = o;
}

__global__ __launch_bounds__(256) void k_encb(
    const float* __restrict__ enc, const int* __restrict__ order_i,
    ushort* __restrict__ encb) {
  int b = blockIdx.y;
  int ob = order_i[b];
  int off = blockIdx.x * 1024 + threadIdx.x * 4;
  float4 v = *(const float4*)(enc + (size_t)ob * (PP * ENCD) + off);
  ushort4 o;
  o.x = f2b(v.x); o.y = f2b(v.y); o.z = f2b(v.z); o.w = f2b(v.w);
  *(ushort4*)(encb + (size_t)b * (PP * ENCD) + off) = o;
}

// ---------------------------------------------------------------------------
__global__ __launch_bounds__(256) void k_transpose(
    const float* __restrict__ src, int R, int C,
    float* __restrict__ dst, int dstLD) {
  __shared__ float tile[32][33];
  int tx = threadIdx.x, ty = threadIdx.y;   // 32 x 8
  int c0 = blockIdx.x * 32, r0 = blockIdx.y * 32;
  for (int i = ty; i < 32; i += 8)
    tile[i][tx] = src[(size_t)(r0 + i) * C + (c0 + tx)];
  __syncthreads();
  for (int i = ty; i < 32; i += 8)
    dst[(size_t)(c0 + i) * dstLD + (r0 + tx)] = tile[tx][i];
}

// ---------------------------------------------------------------------------
__global__ __launch_bounds__(256) void k_mean(
    const float* __restrict__ enc, const int* __restrict__ order_i,
    float* __restrict__ mean_enc) {
  int b = blockIdx.x;
  int ob = order_i[b];
  const float* src = enc + (size_t)ob * PP * ENCD;
  for (int e = threadIdx.x; e < ENCD; e += 256) {
    float acc = 0.f;
    for (int p = 0; p < PP; ++p) acc += src[p * ENCD + e];
    mean_enc[b * ENCD + e] = acc * (1.f / PP);
  }
}

// ---------------------------------------------------------------------------
__global__ __launch_bounds__(256) void k_init_hc(
    const float* __restrict__ mean_enc, const float* __restrict__ WhT,
    const float* __restrict__ bh, const float* __restrict__ WcT,
    const float* __restrict__ bc, ushort* __restrict__ hbt0,
    float* __restrict__ c0) {
  __shared__ float m[ENCD];
  int b = blockIdx.x;
  for (int k = threadIdx.x; k < ENCD; k += 256) m[k] = mean_enc[b * ENCD + k];
  __syncthreads();
  for (int d = threadIdx.x; d < DDIM; d += 256) {
    float ah = bh[d], ac = bc[d];
    for (int k = 0; k < ENCD; ++k) {
      float mv = m[k];
      ah += mv * WhT[k * DDIM + d];
      ac += mv * WcT[k * DDIM + d];
    }
    hbt0[b * DDIM + d] = f2b(ah);
    c0[b * DDIM + d] = ac;
  }
}

// ---------------------------------------------------------------------------
// MFMA GEMM: ea = encb @ W_enc^T + b_enc -> bf16 eab. M=12544, N=512, K=512.
__global__ __launch_bounds__(256) void k_ea_mfma(
    const ushort* __restrict__ encb, const ushort* __restrict__ Wencb,
    const float* __restrict__ b_enc, ushort* __restrict__ eab) {
  int tid = threadIdx.x, wave = tid >> 6, lane = tid & 63;
  int quad = lane >> 4, lr = lane & 15;
  int m0 = blockIdx.y * 64;
  int n0 = blockIdx.x * 128 + wave * 32;
  const ushort* Arow = encb + ((size_t)(m0 + lr)) * 512 + quad * 8;
  const ushort* B0 = Wencb + (size_t)(n0 + lr) * 512 + quad * 8;
  const ushort* B1 = B0 + 16 * 512;
  f32x4 acc[4][2] = {};
  for (int k0 = 0; k0 < 512; k0 += 32) {
    bf16x8 b0 = *reinterpret_cast<const bf16x8*>(B0 + k0);
    bf16x8 b1 = *reinterpret_cast<const bf16x8*>(B1 + k0);
#pragma unroll
    for (int mt = 0; mt < 4; ++mt) {
      bf16x8 a = *reinterpret_cast<const bf16x8*>(Arow + mt * 16 * 512 + k0);
      acc[mt][0] = __builtin_amdgcn_mfma_f32_16x16x32_bf16(a, b0, acc[mt][0], 0, 0, 0);
      acc[mt][1] = __builtin_amdgcn_mfma_f32_16x16x32_bf16(a, b1, acc[mt][1], 0, 0, 0);
    }
  }
#pragma unroll
  for (int mt = 0; mt < 4; ++mt)
#pragma unroll
    for (int nt = 0; nt < 2; ++nt) {
      int col = n0 + nt * 16 + lr;
      float bias = b_enc[col];
#pragma unroll
      for (int r = 0; r < 4; ++r) {
        int row = m0 + mt * 16 + quad * 4 + r;
        eab[(size_t)row * 512 + col] = f2b(acc[mt][nt][r] + bias);
      }
    }
}

// ---------------------------------------------------------------------------
// Lightweight grid barrier among NDECODE blocks: relaxed agent atomics only —
// no cache invalidation, read-only weights stay L2-resident. Monotonic count.
__device__ __forceinline__ void lsync(unsigned* cnt, unsigned* flag,
                                      unsigned& gen) {
  __syncthreads();
  if (threadIdx.x == 0) {
    ++gen;
    asm volatile("s_waitcnt vmcnt(0)" ::: "memory");
    unsigned old = __hip_atomic_fetch_add(cnt, 1u, __ATOMIC_RELAXED,
                                          __HIP_MEMORY_SCOPE_AGENT);
    if (old == gen * NDECODE - 1u) {
      __hip_atomic_store(flag, gen, __ATOMIC_RELAXED,
                         __HIP_MEMORY_SCOPE_AGENT);
    } else {
      while (__hip_atomic_load(flag, __ATOMIC_RELAXED,
                               __HIP_MEMORY_SCOPE_AGENT) < gen)
        __builtin_amdgcn_s_sleep(1);
    }
  }
  __syncthreads();
}

// ---------------------------------------------------------------------------
struct DecodeArgs {
  const ushort* Wdgb;
  const float* b_dec;
  const float* b_fb;
  const ushort* eab;
  const float* w_full;
  const ushort* encb;
  const float* emb_table;
  const int* caps;
  const int* order_i;
  const int* declen_i;
  const ushort* Wcatb;
  const float* b_ih;
  const float* b_hh;
  const float* c0;
  const ushort* Wfcb;
  const float* b_fc;
  ushort* hbt;        // [51][64][512] h history (write-through)
  float* dag;         // [50][64][1024] da|gate (write-through)
  ushort* xct;        // [50][64][1536] xcat (write-through)
  float* out_alphas;
  float* out_pred;
  unsigned* cnt;
  unsigned* flag;
};

// ---------------------------------------------------------------------------
// Persistent kernel: 256 blocks x 512 threads (8 waves), cooperative launch.
// Blocks 0..63  : decode loop, 3 lsync barriers/step.
//   P1: dagate (blocks 0..31, 16 cols each)     -> dag[t]
//   P2: attention (blocks 0..63, 8 waves)       -> xcat[t], alphas
//   P3: gates GEMM + LSTM (blocks 0..63)        -> hbt[t+1]; c in registers
// Blocks 64..255: fc tiles (t,chunk), gated on barrier flag >= 3*(t+1).
__global__ __launch_bounds__(512, 2) void k_decode_loop(DecodeArgs A) {
  __shared__ int dls[BB];
  __shared__ float wf[ADIM];
  __shared__ float das[ADIM];
  __shared__ float sc[PP];
  __shared__ float ctxp[8][512];
  __shared__ float sg[4][32][16];
  int tid = threadIdx.x;
  int bid = blockIdx.x;
  int wave = tid >> 6, lane = tid & 63;
  int quad = lane >> 4, lr = lane & 15;

  if (tid < BB) dls[tid] = A.declen_i[tid];
  __syncthreads();

  if (bid < NDECODE) {
    // =========================== decode path ==============================
    for (int i = tid; i < ADIM; i += 512) wf[i] = A.w_full[i];
    __syncthreads();
    unsigned gen = 0;
    float creg = 0.f;   // P3 cell state: this thread's (row, d) element
    int b = bid;
    // P3 geometry (all 64 blocks): 16 d-cols, half the m-rows each.
    int d0 = (bid >> 1) * 16;
    int mh = bid & 1;
    int g3 = wave & 3, mq = wave >> 2;  // gate, m-quarter within half

    for (int t = 0; t < TSTEPS; ++t) {
      const ushort* hcur = A.hbt + (size_t)t * BB * DDIM;
      float* dagt = A.dag + (size_t)t * BB * 1024;
      ushort* xctt = A.xct + (size_t)t * BB * KCAT;

      // ---- P1: [da | gate] = h_t @ [W_dec;W_f_beta]^T (blocks 0..31) ----
      if (bid < 32) {
        int ct = wave & 1, mt = wave >> 1;            // 2 col-tiles x 4 m-tiles
        int n0 = bid * 32 + ct * 16;
        const ushort* Arow = hcur + (size_t)(mt * 16 + lr) * 512 + quad * 8;
        const ushort* Bp = A.Wdgb + (size_t)(n0 + lr) * 512 + quad * 8;
        f32x4 acc = {};
        for (int k0 = 0; k0 < 512; k0 += 32) {
          bf16x8 bfr = *reinterpret_cast<const bf16x8*>(Bp + k0);
          bf16x8 a = *reinterpret_cast<const bf16x8*>(Arow + k0);
          acc = __builtin_amdgcn_mfma_f32_16x16x32_bf16(a, bfr, acc, 0, 0, 0);
        }
        int col = n0 + lr;
#pragma unroll
        for (int r = 0; r < 4; ++r) {
          int row = mt * 16 + quad * 4 + r;
          float v = acc[r];
          if (col < 512) {
            st_wt_f32(&dagt[row * 1024 + col], v + A.b_dec[col]);
          } else {
            int cg = col - 512;
            st_wt_f32(&dagt[row * 1024 + 512 + cg],
                      1.f / (1.f + expf(-(v + A.b_fb[cg]))));
          }
        }
      }
      lsync(A.cnt, A.flag, gen);

      // ---- P2: attention (blocks 0..63, block b = batch b) ----
      {
        das[tid] = dagt[b * 1024 + tid];
        int tok = A.caps[A.order_i[b] * MAXLEN + t];
        st_wt_u16(&xctt[(size_t)b * KCAT + tid],
                  f2b(A.emb_table[(size_t)tok * EDIM + tid]));
        st_wt_u16(&xctt[(size_t)b * KCAT + 1024 + tid], hcur[b * 512 + tid]);
        __syncthreads();
        // scores over p, 8 waves
        for (int p = wave; p < PP; p += 8) {
          const ushort* ep = A.eab + ((size_t)b * PP + p) * ADIM + lane * 8;
          bf16x8 ev = *reinterpret_cast<const bf16x8*>(ep);
          float s = 0.f;
#pragma unroll
          for (int j = 0; j < 8; ++j) {
            int a = lane * 8 + j;
            float e = b2f((ushort)ev[j]);
            s += fmaxf(e + das[a], 0.f) * wf[a];
          }
#pragma unroll
          for (int off = 32; off; off >>= 1) s += __shfl_xor(s, off);
          if (lane == 0) sc[p] = s;
        }
        __syncthreads();
        if (wave == 0) {  // softmax over 196
          float m = -1e30f;
          for (int p = lane; p < PP; p += 64) m = fmaxf(m, sc[p]);
#pragma unroll
          for (int off = 32; off; off >>= 1) m = fmaxf(m, __shfl_xor(m, off));
          float ssum = 0.f;
          for (int p = lane; p < PP; p += 64) {
            float e = expf(sc[p] - m);
            sc[p] = e;
            ssum += e;
          }
#pragma unroll
          for (int off = 32; off; off >>= 1) ssum += __shfl_xor(ssum, off);
          float inv = 1.f / ssum;
          for (int p = lane; p < PP; p += 64) sc[p] *= inv;
        }
        __syncthreads();
        int active = t < dls[b];
        for (int p = tid; p < PP; p += 512)
          A.out_alphas[((size_t)b * TSTEPS + t) * PP + p] = active ? sc[p] : 0.f;
        // ctx: thread = (e-group of 8, p-group); 16B loads, LDS reduce
        int e8 = tid & 63, pg = tid >> 6;
        float a8[8] = {0.f, 0.f, 0.f, 0.f, 0.f, 0.f, 0.f, 0.f};
        const ushort* eb = A.encb + (size_t)b * (PP * ENCD) + e8 * 8;
        for (int p = pg; p < PP; p += 8) {
          float al = sc[p];
          bf16x8 ev = *reinterpret_cast<const bf16x8*>(eb + (size_t)p * ENCD);
#pragma unroll
          for (int j = 0; j < 8; ++j) a8[j] += al * b2f((ushort)ev[j]);
        }
#pragma unroll
        for (int j = 0; j < 8; ++j) ctxp[pg][e8 * 8 + j] = a8[j];
        __syncthreads();
        float cx = 0.f;
#pragma unroll
        for (int g = 0; g < 8; ++g) cx += ctxp[g][tid];
        cx *= dagt[b * 1024 + 512 + tid];
        st_wt_u16(&xctt[(size_t)b * KCAT + 512 + tid], f2b(cx));
        __syncthreads();
      }
      lsync(A.cnt, A.flag, gen);

      // ---- P3: gates GEMM + fused LSTM (all 64 blocks) ----
      {
        int mt = mh * 2 + mq;
        int colbase = g3 * 512 + d0;
        const ushort* Arow = xctt + (size_t)(mt * 16 + lr) * KCAT + quad * 8;
        const ushort* Bp = A.Wcatb + (size_t)(colbase + lr) * KCAT + quad * 8;
        f32x4 acc = {};
        for (int k0 = 0; k0 < KCAT; k0 += 32) {
          bf16x8 bfr = *reinterpret_cast<const bf16x8*>(Bp + k0);
          bf16x8 a = *reinterpret_cast<const bf16x8*>(Arow + k0);
          acc = __builtin_amdgcn_mfma_f32_16x16x32_bf16(a, bfr, acc, 0, 0, 0);
        }
#pragma unroll
        for (int r = 0; r < 4; ++r)
          sg[g3][mq * 16 + quad * 4 + r][lr] = acc[r];
        __syncthreads();
        ushort* hnext = A.hbt + (size_t)(t + 1) * BB * DDIM;
        int rowl = tid >> 4, dd = tid & 15;
        int row = mh * 32 + rowl;
        int d = d0 + dd;
        float gi = sg[0][rowl][dd] + A.b_ih[d] + A.b_hh[d];
        float gf = sg[1][rowl][dd] + A.b_ih[512 + d] + A.b_hh[512 + d];
        float gg = sg[2][rowl][dd] + A.b_ih[1024 + d] + A.b_hh[1024 + d];
        float go = sg[3][rowl][dd] + A.b_ih[1536 + d] + A.b_hh[1536 + d];
        float si = 1.f / (1.f + expf(-gi));
        float sf = 1.f / (1.f + expf(-gf));
        float so = 1.f / (1.f + expf(-go));
        if (t == 0) creg = A.c0[row * DDIM + d];
        float cn = sf * creg + si * tanhf(gg);
        creg = cn;
        float hn = so * tanhf(cn);
        st_wt_u16(&hnext[row * DDIM + d], f2b(hn));
        __syncthreads();
      }
      lsync(A.cnt, A.flag, gen);
    }
  } else {
    // ============================ fc path =================================
    // Tiles (t, chunk): 50 x 125, t-major; gated on flag >= 3*(t+1).
    int fcid = bid - NDECODE;
    for (int tile = fcid; tile < FCTILES; tile += (GRID_TOTAL - NDECODE)) {
      int t = tile / 125;
      int chunk = tile - t * 125;
      if (tid == 0) {
        unsigned need = 3u * (unsigned)(t + 1);
        while (__hip_atomic_load(A.flag, __ATOMIC_RELAXED,
                                 __HIP_MEMORY_SCOPE_AGENT) < need)
          __builtin_amdgcn_s_sleep(8);
      }
      __syncthreads();
      int n0 = chunk * 256 + wave * 32;
      const ushort* Arow = A.hbt + (size_t)(t + 1) * BB * DDIM +
                           (size_t)lr * 512 + quad * 8;
      const ushort* B0 = A.Wfcb + (size_t)(n0 + lr) * 512 + quad * 8;
      const ushort* B1 = B0 + 16 * 512;
      f32x4 acc[4][2] = {};
      for (int k0 = 0; k0 < 512; k0 += 32) {
        bf16x8 b0 = *reinterpret_cast<const bf16x8*>(B0 + k0);
        bf16x8 b1 = *reinterpret_cast<const bf16x8*>(B1 + k0);
#pragma unroll
        for (int mt = 0; mt < 4; ++mt) {
          bf16x8 a = *reinterpret_cast<const bf16x8*>(Arow + mt * 16 * 512 + k0);
          acc[mt][0] = __builtin_amdgcn_mfma_f32_16x16x32_bf16(a, b0, acc[mt][0], 0, 0, 0);
          acc[mt][1] = __builtin_amdgcn_mfma_f32_16x16x32_bf16(a, b1, acc[mt][1], 0, 0, 0);
        }
      }
#pragma unroll
      for (int mt = 0; mt < 4; ++mt)
#pragma unroll
        for (int nt = 0; nt < 2; ++nt) {
          int col = n0 + nt * 16 + lr;
          float bias = A.b_fc[col];
#pragma unroll
          for (int r = 0; r < 4; ++r) {
            int row = mt * 16 + quad * 4 + r;
            int active = t < dls[row];
            A.out_pred[((size_t)row * TSTEPS + t) * VDIM + col] =
                active ? (acc[mt][nt][r] + bias) : 0.f;
          }
        }
      __syncthreads();
    }
  }
}

// ---------------------------------------------------------------------------
extern "C" void kernel_launch(void* const* d_in, const int* in_sizes, int n_in,
                              void* d_out, int out_size, void* d_ws,
                              size_t ws_size, hipStream_t stream) {
  const float* encoder_out = (const float*)d_in[0];
  const int* encoded_captions = (const int*)d_in[1];
  const int* cap_len = (const int*)d_in[2];
  const float* W_enc = (const float*)d_in[3];
  const float* b_enc = (const float*)d_in[4];
  const float* W_dec = (const float*)d_in[5];
  const float* b_dec = (const float*)d_in[6];
  const float* w_full = (const float*)d_in[7];
  // d_in[8] = b_full (scalar; softmax-invariant, omitted)
  const float* emb_table = (const float*)d_in[9];
  const float* W_ih = (const float*)d_in[10];
  const float* W_hh = (const float*)d_in[11];
  const float* b_ih = (const float*)d_in[12];
  const float* b_hh = (const float*)d_in[13];
  const float* W_init_h = (const float*)d_in[14];
  const float* b_init_h = (const float*)d_in[15];
  const float* W_init_c = (const float*)d_in[16];
  const float* b_init_c = (const float*)d_in[17];
  const float* W_f_beta = (const float*)d_in[18];
  const float* b_f_beta = (const float*)d_in[19];
  const float* W_fc = (const float*)d_in[20];
  const float* b_fc = (const float*)d_in[21];

  float* out = (float*)d_out;
  float* out_pred = out;
  float* out_caps = out_pred + (size_t)BB * TSTEPS * VDIM;
  float* out_declen = out_caps + BB * MAXLEN;
  float* out_alphas = out_declen + BB;
  float* out_order = out_alphas + (size_t)BB * TSTEPS * PP;

  char* base = (char*)d_ws;
  ushort* Wfcb = (ushort*)(base + OFF_WFCB);
  ushort* Wcatb = (ushort*)(base + OFF_WCATB);
  ushort* Wdgb = (ushort*)(base + OFF_WDGB);
  ushort* Wencb = (ushort*)(base + OFF_WENCB);
  ushort* encb = (ushort*)(base + OFF_ENCB);
  ushort* eab = (ushort*)(base + OFF_EAB);
  float* WihT = (float*)(base + OFF_WIHT);
  float* WicT = (float*)(base + OFF_WICT);
  float* meanb = (float*)(base + OFF_MEAN);
  float* c0 = (float*)(base + OFF_C0);
  ushort* hbt = (ushort*)(base + OFF_HBT);
  float* dag = (float*)(base + OFF_DAG);
  ushort* xct = (ushort*)(base + OFF_XCT);
  int* order_i = (int*)(base + OFF_ORDER);
  int* declen_i = (int*)(base + OFF_DECLEN);
  unsigned* bar = (unsigned*)(base + OFF_BAR);

  dim3 tb(32, 8);
  k_sort<<<1, 64, 0, stream>>>(cap_len, encoded_captions, out_caps, out_declen,
                               out_order, order_i, declen_i, bar);
  // weight conversions (one-time per call)
  k_cvt<<<2048, 256, 0, stream>>>(W_fc, Wfcb, 16384000 / 4);
  k_cvt<<<64, 256, 0, stream>>>(W_enc, Wencb, 262144 / 4);
  k_cvt_cat<<<2048, 384, 0, stream>>>(W_ih, W_hh, Wcatb);
  k_cvt_dg<<<1024, 128, 0, stream>>>(W_dec, W_f_beta, Wdgb);
  k_encb<<<dim3(98, 64), 256, 0, stream>>>(encoder_out, order_i, encb);
  k_transpose<<<dim3(16, 16), tb, 0, stream>>>(W_init_h, 512, 512, WihT, 512);
  k_transpose<<<dim3(16, 16), tb, 0, stream>>>(W_init_c, 512, 512, WicT, 512);
  // prologue compute
  k_mean<<<64, 256, 0, stream>>>(encoder_out, order_i, meanb);
  k_init_hc<<<64, 256, 0, stream>>>(meanb, WihT, b_init_h, WicT, b_init_c,
                                    hbt, c0);
  k_ea_mfma<<<dim3(4, 196), 256, 0, stream>>>(encb, Wencb, b_enc, eab);

  // persistent decode + overlapped fc: 256 blocks x 512 threads cooperative
  DecodeArgs hargs;
  hargs.Wdgb = Wdgb; hargs.b_dec = b_dec; hargs.b_fb = b_f_beta;
  hargs.eab = eab; hargs.w_full = w_full; hargs.encb = encb;
  hargs.emb_table = emb_table; hargs.caps = encoded_captions;
  hargs.order_i = order_i; hargs.declen_i = declen_i;
  hargs.Wcatb = Wcatb; hargs.b_ih = b_ih; hargs.b_hh = b_hh;
  hargs.c0 = c0; hargs.Wfcb = Wfcb; hargs.b_fc = b_fc;
  hargs.hbt = hbt; hargs.dag = dag; hargs.xct = xct;
  hargs.out_alphas = out_alphas; hargs.out_pred = out_pred;
  hargs.cnt = bar; hargs.flag = bar + 16;
  void* kargs[] = { (void*)&hargs };
  hipLaunchCooperativeKernel((const void*)k_decode_loop, dim3(GRID_TOTAL),
                             dim3(512), kargs, 0, stream);
}

// Round 5
// 4029.411 us; speedup vs baseline: 2.6088x; 1.0007x over previous
//
#include <hip/hip_runtime.h>
#include <hip/hip_bf16.h>
#include <math.h>

// Problem constants
#define BB      64
#define PP      196      // 14*14
#define ENCD    512
#define ADIM    512
#define DDIM    512
#define EDIM    512
#define VDIM    32000
#define MAXLEN  51
#define TSTEPS  50       // MAXLEN - 1
#define KCAT    1536     // E + ENC + D
#define GDIM    2048     // 4*D

#define NDECODE 64        // decode blocks (barrier participants)
#define NFC     125       // fc blocks: one per 256-col W_fc chunk
#define GRID_TOTAL (NDECODE + NFC)

typedef __attribute__((ext_vector_type(8))) short bf16x8;
typedef __attribute__((ext_vector_type(4))) float f32x4;

__device__ __forceinline__ ushort f2b(float x) {
  __hip_bfloat16 h = __float2bfloat16(x);
  return *reinterpret_cast<ushort*>(&h);
}
__device__ __forceinline__ float b2f(ushort u) {
  unsigned v = ((unsigned)u) << 16;
  return __uint_as_float(v);
}

// Cross-XCD write-through stores: visible at L3 without cache maintenance.
// Readers use NORMAL loads of t-indexed fresh addresses (first touch misses
// local L2 -> L3 has the data). No acquire fences => weights stay L2-resident.
__device__ __forceinline__ void st_wt_f32(float* p, float v) {
  __hip_atomic_store(p, v, __ATOMIC_RELAXED, __HIP_MEMORY_SCOPE_AGENT);
}
__device__ __forceinline__ void st_wt_u16(ushort* p, ushort v) {
  __hip_atomic_store(p, v, __ATOMIC_RELAXED, __HIP_MEMORY_SCOPE_AGENT);
}

// Nontemporal access: stream W_fc from L3 without evicting decode's
// L2-resident working set; preds/alphas are write-once.
__device__ __forceinline__ bf16x8 nt_ld8(const ushort* p) {
  return __builtin_nontemporal_load(reinterpret_cast<const bf16x8*>(p));
}
__device__ __forceinline__ void nt_st_f32(float* p, float v) {
  __builtin_nontemporal_store(v, p);
}

// ---------------------------------------------------------------------------
// Workspace layout (byte offsets), total ~95 MB.
#define OFF_WFCB   0ull            // 32,768,000  bf16 W_fc (32000x512)
#define OFF_WCATB  32768000ull     //  6,291,456  bf16 [W_ih|W_hh] (2048x1536)
#define OFF_WDGB   39059456ull     //  1,048,576  bf16 [W_dec;W_f_beta] (1024x512)
#define OFF_WENCB  40108032ull     //    524,288  bf16 W_enc (512x512)
#define OFF_ENCB   40632320ull     // 12,845,056  bf16 enc sorted (64x196x512)
#define OFF_EAB    53477376ull     // 12,845,056  bf16 ea (64x196x512)
#define OFF_WIHT   66322432ull     //  1,048,576  f32 W_init_h^T
#define OFF_WICT   67371008ull     //  1,048,576  f32 W_init_c^T
#define OFF_MEAN   68419584ull     //    131,072  f32 mean_enc
#define OFF_C0     68550656ull     //    131,072  f32 c0
#define OFF_HBT    68681728ull     //  3,342,336  bf16 h history [51][64][512]
#define OFF_DAG    72024064ull     // 13,107,200  f32 [50][64][1024] da|gate
#define OFF_XCT    85131264ull     //  9,830,400  bf16 [50][64][1536] xcat
#define OFF_ORDER  94961664ull
#define OFF_DECLEN 94961920ull
#define OFF_BAR    94962176ull     // barrier: cnt @ [0], flag @ [16]

// ---------------------------------------------------------------------------
__global__ __launch_bounds__(64) void k_sort(
    const int* __restrict__ cap_len, const int* __restrict__ caps,
    float* __restrict__ out_caps, float* __restrict__ out_declen,
    float* __restrict__ out_order, int* __restrict__ order_i,
    int* __restrict__ declen_i, unsigned* __restrict__ bar) {
  __shared__ int lens[BB];
  __shared__ int ord[BB];
  int i = threadIdx.x;
  bar[i] = 0u;  // zero barrier region (cnt @0, flag @16)
  lens[i] = cap_len[i];
  __syncthreads();
  int li = lens[i];
  int rank = 0;
  for (int j = 0; j < BB; ++j) {
    int lj = lens[j];
    if (lj > li || (lj == li && j < i)) rank++;
  }
  ord[rank] = i;
  __syncthreads();
  int ob = ord[i];
  order_i[i] = ob;
  int dl = lens[ob] - 1;
  declen_i[i] = dl;
  out_declen[i] = (float)dl;
  out_order[i] = (float)ob;
  for (int j = 0; j < MAXLEN; ++j)
    out_caps[i * MAXLEN + j] = (float)caps[ob * MAXLEN + j];
}

// ---------------------------------------------------------------------------
__global__ __launch_bounds__(256) void k_cvt(
    const float* __restrict__ src, ushort* __restrict__ dst, int n4) {
  for (int i = blockIdx.x * 256 + threadIdx.x; i < n4; i += gridDim.x * 256) {
    float4 v = *(const float4*)(src + 4 * (size_t)i);
    ushort4 o;
    o.x = f2b(v.x); o.y = f2b(v.y); o.z = f2b(v.z); o.w = f2b(v.w);
    *(ushort4*)(dst + 4 * (size_t)i) = o;
  }
}

__global__ __launch_bounds__(384) void k_cvt_cat(
    const float* __restrict__ W_ih, const float* __restrict__ W_hh,
    ushort* __restrict__ dst) {
  int n = blockIdx.x;
  int k = threadIdx.x * 4;
  const float* src = (k < 1024) ? (W_ih + (size_t)n * 1024 + k)
                                : (W_hh + (size_t)n * 512 + (k - 1024));
  float4 v = *(const float4*)src;
  ushort4 o;
  o.x = f2b(v.x); o.y = f2b(v.y); o.z = f2b(v.z); o.w = f2b(v.w);
  *(ushort4*)(dst + (size_t)n * KCAT + k) = o;
}

__global__ __launch_bounds__(128) void k_cvt_dg(
    const float* __restrict__ W_dec, const float* __restrict__ W_fb,
    ushort* __restrict__ dst) {
  int n = blockIdx.x;
  int k = threadIdx.x * 4;
  const float* src = (n < 512) ? (W_dec + (size_t)n * 512 + k)
                               : (W_fb + (size_t)(n - 512) * 512 + k);
  float4 v = *(const float4*)src;
  ushort4 o;
  o.x = f2b(v.x); o.y = f2b(v.y); o.z = f2b(v.z); o.w = f2b(v.w);
  *(ushort4*)(dst + (size_t)n * 512 + k) = o;
}

__global__ __launch_bounds__(256) void k_encb(
    const float* __restrict__ enc, const int* __restrict__ order_i,
    ushort* __restrict__ encb) {
  int b = blockIdx.y;
  int ob = order_i[b];
  int off = blockIdx.x * 1024 + threadIdx.x * 4;
  float4 v = *(const float4*)(enc + (size_t)ob * (PP * ENCD) + off);
  ushort4 o;
  o.x = f2b(v.x); o.y = f2b(v.y); o.z = f2b(v.z); o.w = f2b(v.w);
  *(ushort4*)(encb + (size_t)b * (PP * ENCD) + off) = o;
}

// ---------------------------------------------------------------------------
__global__ __launch_bounds__(256) void k_transpose(
    const float* __restrict__ src, int R, int C,
    float* __restrict__ dst, int dstLD) {
  __shared__ float tile[32][33];
  int tx = threadIdx.x, ty = threadIdx.y;   // 32 x 8
  int c0 = blockIdx.x * 32, r0 = blockIdx.y * 32;
  for (int i = ty; i < 32; i += 8)
    tile[i][tx] = src[(size_t)(r0 + i) * C + (c0 + tx)];
  __syncthreads();
  for (int i = ty; i < 32; i += 8)
    dst[(size_t)(c0 + i) * dstLD + (r0 + tx)] = tile[tx][i];
}

// ---------------------------------------------------------------------------
__global__ __launch_bounds__(256) void k_mean(
    const float* __restrict__ enc, const int* __restrict__ order_i,
    float* __restrict__ mean_enc) {
  int b = blockIdx.x;
  int ob = order_i[b];
  const float* src = enc + (size_t)ob * PP * ENCD;
  for (int e = threadIdx.x; e < ENCD; e += 256) {
    float acc = 0.f;
    for (int p = 0; p < PP; ++p) acc += src[p * ENCD + e];
    mean_enc[b * ENCD + e] = acc * (1.f / PP);
  }
}

// ---------------------------------------------------------------------------
__global__ __launch_bounds__(256) void k_init_hc(
    const float* __restrict__ mean_enc, const float* __restrict__ WhT,
    const float* __restrict__ bh, const float* __restrict__ WcT,
    const float* __restrict__ bc, ushort* __restrict__ hbt0,
    float* __restrict__ c0) {
  __shared__ float m[ENCD];
  int b = blockIdx.x;
  for (int k = threadIdx.x; k < ENCD; k += 256) m[k] = mean_enc[b * ENCD + k];
  __syncthreads();
  for (int d = threadIdx.x; d < DDIM; d += 256) {
    float ah = bh[d], ac = bc[d];
    for (int k = 0; k < ENCD; ++k) {
      float mv = m[k];
      ah += mv * WhT[k * DDIM + d];
      ac += mv * WcT[k * DDIM + d];
    }
    hbt0[b * DDIM + d] = f2b(ah);
    c0[b * DDIM + d] = ac;
  }
}

// ---------------------------------------------------------------------------
// MFMA GEMM: ea = encb @ W_enc^T + b_enc -> bf16 eab. M=12544, N=512, K=512.
__global__ __launch_bounds__(256) void k_ea_mfma(
    const ushort* __restrict__ encb, const ushort* __restrict__ Wencb,
    const float* __restrict__ b_enc, ushort* __restrict__ eab) {
  int tid = threadIdx.x, wave = tid >> 6, lane = tid & 63;
  int quad = lane >> 4, lr = lane & 15;
  int m0 = blockIdx.y * 64;
  int n0 = blockIdx.x * 128 + wave * 32;
  const ushort* Arow = encb + ((size_t)(m0 + lr)) * 512 + quad * 8;
  const ushort* B0 = Wencb + (size_t)(n0 + lr) * 512 + quad * 8;
  const ushort* B1 = B0 + 16 * 512;
  f32x4 acc[4][2] = {};
  for (int k0 = 0; k0 < 512; k0 += 32) {
    bf16x8 b0 = *reinterpret_cast<const bf16x8*>(B0 + k0);
    bf16x8 b1 = *reinterpret_cast<const bf16x8*>(B1 + k0);
#pragma unroll
    for (int mt = 0; mt < 4; ++mt) {
      bf16x8 a = *reinterpret_cast<const bf16x8*>(Arow + mt * 16 * 512 + k0);
      acc[mt][0] = __builtin_amdgcn_mfma_f32_16x16x32_bf16(a, b0, acc[mt][0], 0, 0, 0);
      acc[mt][1] = __builtin_amdgcn_mfma_f32_16x16x32_bf16(a, b1, acc[mt][1], 0, 0, 0);
    }
  }
#pragma unroll
  for (int mt = 0; mt < 4; ++mt)
#pragma unroll
    for (int nt = 0; nt < 2; ++nt) {
      int col = n0 + nt * 16 + lr;
      float bias = b_enc[col];
#pragma unroll
      for (int r = 0; r < 4; ++r) {
        int row = m0 + mt * 16 + quad * 4 + r;
        eab[(size_t)row * 512 + col] = f2b(acc[mt][nt][r] + bias);
      }
    }
}

// ---------------------------------------------------------------------------
// Lightweight grid barrier among NDECODE blocks: relaxed agent atomics only —
// no cache invalidation, read-only weights stay L2-resident. Monotonic count.
__device__ __forceinline__ void lsync(unsigned* cnt, unsigned* flag,
                                      unsigned& gen) {
  __syncthreads();
  if (threadIdx.x == 0) {
    ++gen;
    asm volatile("s_waitcnt vmcnt(0)" ::: "memory");
    unsigned old = __hip_atomic_fetch_add(cnt, 1u, __ATOMIC_RELAXED,
                                          __HIP_MEMORY_SCOPE_AGENT);
    if (old == gen * NDECODE - 1u) {
      __hip_atomic_store(flag, gen, __ATOMIC_RELAXED,
                         __HIP_MEMORY_SCOPE_AGENT);
    } else {
      while (__hip_atomic_load(flag, __ATOMIC_RELAXED,
                               __HIP_MEMORY_SCOPE_AGENT) < gen)
        __builtin_amdgcn_s_sleep(1);
    }
  }
  __syncthreads();
}

// ---------------------------------------------------------------------------
struct DecodeArgs {
  const ushort* Wdgb;
  const float* b_dec;
  const float* b_fb;
  const ushort* eab;
  const float* w_full;
  const ushort* encb;
  const float* emb_table;
  const int* caps;
  const int* order_i;
  const int* declen_i;
  const ushort* Wcatb;
  const float* b_ih;
  const float* b_hh;
  const float* c0;
  const ushort* Wfcb;
  const float* b_fc;
  ushort* hbt;        // [51][64][512] h history (write-through)
  float* dag;         // [50][64][1024] da|gate (write-through)
  ushort* xct;        // [50][64][1536] xcat (write-through)
  float* out_alphas;
  float* out_pred;
  unsigned* cnt;
  unsigned* flag;
};

// ---------------------------------------------------------------------------
// Persistent kernel: 189 blocks x 512 threads (8 waves), cooperative launch.
// Blocks 0..63  : decode loop, 3 lsync barriers/step.
//   P1: dagate (blocks 0..31, 16 cols each)     -> dag[t]
//   P2: attention (blocks 0..63, 8 waves)       -> xcat[t], alphas
//   P3: gates GEMM + LSTM (blocks 0..63)        -> hbt[t+1]; c in registers
// Blocks 64..188: fc, chunk-owned — block owns one 256-col W_fc chunk and
//   iterates t (gated on flag >= 3*(t+1)). W_fc via NONTEMPORAL loads (stream
//   from L3, keep L2 for decode); preds via nontemporal stores.
__global__ __launch_bounds__(512, 2) void k_decode_loop(DecodeArgs A) {
  __shared__ int dls[BB];
  __shared__ float wf[ADIM];
  __shared__ float das[ADIM];
  __shared__ float sc[PP];
  __shared__ float ctxp[8][512];
  __shared__ float sg[4][32][16];
  int tid = threadIdx.x;
  int bid = blockIdx.x;
  int wave = tid >> 6, lane = tid & 63;
  int quad = lane >> 4, lr = lane & 15;

  if (tid < BB) dls[tid] = A.declen_i[tid];
  __syncthreads();

  if (bid < NDECODE) {
    // =========================== decode path ==============================
    for (int i = tid; i < ADIM; i += 512) wf[i] = A.w_full[i];
    __syncthreads();
    unsigned gen = 0;
    float creg = 0.f;   // P3 cell state: this thread's (row, d) element
    int b = bid;
    // P3 geometry (all 64 blocks): 16 d-cols, half the m-rows each.
    int d0 = (bid >> 1) * 16;
    int mh = bid & 1;
    int g3 = wave & 3, mq = wave >> 2;  // gate, m-quarter within half

    for (int t = 0; t < TSTEPS; ++t) {
      const ushort* hcur = A.hbt + (size_t)t * BB * DDIM;
      float* dagt = A.dag + (size_t)t * BB * 1024;
      ushort* xctt = A.xct + (size_t)t * BB * KCAT;

      // ---- P1: [da | gate] = h_t @ [W_dec;W_f_beta]^T (blocks 0..31) ----
      if (bid < 32) {
        int ct = wave & 1, mt = wave >> 1;            // 2 col-tiles x 4 m-tiles
        int n0 = bid * 32 + ct * 16;
        const ushort* Arow = hcur + (size_t)(mt * 16 + lr) * 512 + quad * 8;
        const ushort* Bp = A.Wdgb + (size_t)(n0 + lr) * 512 + quad * 8;
        f32x4 acc = {};
        for (int k0 = 0; k0 < 512; k0 += 32) {
          bf16x8 bfr = *reinterpret_cast<const bf16x8*>(Bp + k0);
          bf16x8 a = *reinterpret_cast<const bf16x8*>(Arow + k0);
          acc = __builtin_amdgcn_mfma_f32_16x16x32_bf16(a, bfr, acc, 0, 0, 0);
        }
        int col = n0 + lr;
#pragma unroll
        for (int r = 0; r < 4; ++r) {
          int row = mt * 16 + quad * 4 + r;
          float v = acc[r];
          if (col < 512) {
            st_wt_f32(&dagt[row * 1024 + col], v + A.b_dec[col]);
          } else {
            int cg = col - 512;
            st_wt_f32(&dagt[row * 1024 + 512 + cg],
                      1.f / (1.f + expf(-(v + A.b_fb[cg]))));
          }
        }
      }
      lsync(A.cnt, A.flag, gen);

      // ---- P2: attention (blocks 0..63, block b = batch b) ----
      {
        das[tid] = dagt[b * 1024 + tid];
        int tok = A.caps[A.order_i[b] * MAXLEN + t];
        st_wt_u16(&xctt[(size_t)b * KCAT + tid],
                  f2b(A.emb_table[(size_t)tok * EDIM + tid]));
        st_wt_u16(&xctt[(size_t)b * KCAT + 1024 + tid], hcur[b * 512 + tid]);
        __syncthreads();
        // scores over p, 8 waves
        for (int p = wave; p < PP; p += 8) {
          const ushort* ep = A.eab + ((size_t)b * PP + p) * ADIM + lane * 8;
          bf16x8 ev = *reinterpret_cast<const bf16x8*>(ep);
          float s = 0.f;
#pragma unroll
          for (int j = 0; j < 8; ++j) {
            int a = lane * 8 + j;
            float e = b2f((ushort)ev[j]);
            s += fmaxf(e + das[a], 0.f) * wf[a];
          }
#pragma unroll
          for (int off = 32; off; off >>= 1) s += __shfl_xor(s, off);
          if (lane == 0) sc[p] = s;
        }
        __syncthreads();
        if (wave == 0) {  // softmax over 196
          float m = -1e30f;
          for (int p = lane; p < PP; p += 64) m = fmaxf(m, sc[p]);
#pragma unroll
          for (int off = 32; off; off >>= 1) m = fmaxf(m, __shfl_xor(m, off));
          float ssum = 0.f;
          for (int p = lane; p < PP; p += 64) {
            float e = expf(sc[p] - m);
            sc[p] = e;
            ssum += e;
          }
#pragma unroll
          for (int off = 32; off; off >>= 1) ssum += __shfl_xor(ssum, off);
          float inv = 1.f / ssum;
          for (int p = lane; p < PP; p += 64) sc[p] *= inv;
        }
        __syncthreads();
        int active = t < dls[b];
        for (int p = tid; p < PP; p += 512)
          nt_st_f32(&A.out_alphas[((size_t)b * TSTEPS + t) * PP + p],
                    active ? sc[p] : 0.f);
        // ctx: thread = (e-group of 8, p-group); 16B loads, LDS reduce
        int e8 = tid & 63, pg = tid >> 6;
        float a8[8] = {0.f, 0.f, 0.f, 0.f, 0.f, 0.f, 0.f, 0.f};
        const ushort* eb = A.encb + (size_t)b * (PP * ENCD) + e8 * 8;
        for (int p = pg; p < PP; p += 8) {
          float al = sc[p];
          bf16x8 ev = *reinterpret_cast<const bf16x8*>(eb + (size_t)p * ENCD);
#pragma unroll
          for (int j = 0; j < 8; ++j) a8[j] += al * b2f((ushort)ev[j]);
        }
#pragma unroll
        for (int j = 0; j < 8; ++j) ctxp[pg][e8 * 8 + j] = a8[j];
        __syncthreads();
        float cx = 0.f;
#pragma unroll
        for (int g = 0; g < 8; ++g) cx += ctxp[g][tid];
        cx *= dagt[b * 1024 + 512 + tid];
        st_wt_u16(&xctt[(size_t)b * KCAT + 512 + tid], f2b(cx));
        __syncthreads();
      }
      lsync(A.cnt, A.flag, gen);

      // ---- P3: gates GEMM + fused LSTM (all 64 blocks) ----
      {
        int mt = mh * 2 + mq;
        int colbase = g3 * 512 + d0;
        const ushort* Arow = xctt + (size_t)(mt * 16 + lr) * KCAT + quad * 8;
        const ushort* Bp = A.Wcatb + (size_t)(colbase + lr) * KCAT + quad * 8;
        f32x4 acc = {};
        for (int k0 = 0; k0 < KCAT; k0 += 32) {
          bf16x8 bfr = *reinterpret_cast<const bf16x8*>(Bp + k0);
          bf16x8 a = *reinterpret_cast<const bf16x8*>(Arow + k0);
          acc = __builtin_amdgcn_mfma_f32_16x16x32_bf16(a, bfr, acc, 0, 0, 0);
        }
#pragma unroll
        for (int r = 0; r < 4; ++r)
          sg[g3][mq * 16 + quad * 4 + r][lr] = acc[r];
        __syncthreads();
        ushort* hnext = A.hbt + (size_t)(t + 1) * BB * DDIM;
        int rowl = tid >> 4, dd = tid & 15;
        int row = mh * 32 + rowl;
        int d = d0 + dd;
        float gi = sg[0][rowl][dd] + A.b_ih[d] + A.b_hh[d];
        float gf = sg[1][rowl][dd] + A.b_ih[512 + d] + A.b_hh[512 + d];
        float gg = sg[2][rowl][dd] + A.b_ih[1024 + d] + A.b_hh[1024 + d];
        float go = sg[3][rowl][dd] + A.b_ih[1536 + d] + A.b_hh[1536 + d];
        float si = 1.f / (1.f + expf(-gi));
        float sf = 1.f / (1.f + expf(-gf));
        float so = 1.f / (1.f + expf(-go));
        if (t == 0) creg = A.c0[row * DDIM + d];
        float cn = sf * creg + si * tanhf(gg);
        creg = cn;
        float hn = so * tanhf(cn);
        st_wt_u16(&hnext[row * DDIM + d], f2b(hn));
        __syncthreads();
      }
      lsync(A.cnt, A.flag, gen);
    }
  } else {
    // ============================ fc path =================================
    // Block owns W_fc chunk (256 cols); iterates t gated on flag >= 3*(t+1).
    // W_fc read nontemporal (L3 stream, no L2 pollution); preds stored nt.
    int chunk = bid - NDECODE;   // 0..124
    int n0 = chunk * 256 + wave * 32;
    const ushort* B0 = A.Wfcb + (size_t)(n0 + lr) * 512 + quad * 8;
    const ushort* B1 = B0 + 16 * 512;
    for (int t = 0; t < TSTEPS; ++t) {
      if (tid == 0) {
        unsigned need = 3u * (unsigned)(t + 1);
        while (__hip_atomic_load(A.flag, __ATOMIC_RELAXED,
                                 __HIP_MEMORY_SCOPE_AGENT) < need)
          __builtin_amdgcn_s_sleep(16);
      }
      __syncthreads();
      const ushort* Arow = A.hbt + (size_t)(t + 1) * BB * DDIM +
                           (size_t)lr * 512 + quad * 8;
      f32x4 acc[4][2] = {};
      for (int k0 = 0; k0 < 512; k0 += 32) {
        bf16x8 b0 = nt_ld8(B0 + k0);
        bf16x8 b1 = nt_ld8(B1 + k0);
#pragma unroll
        for (int mt = 0; mt < 4; ++mt) {
          bf16x8 a = *reinterpret_cast<const bf16x8*>(Arow + mt * 16 * 512 + k0);
          acc[mt][0] = __builtin_amdgcn_mfma_f32_16x16x32_bf16(a, b0, acc[mt][0], 0, 0, 0);
          acc[mt][1] = __builtin_amdgcn_mfma_f32_16x16x32_bf16(a, b1, acc[mt][1], 0, 0, 0);
        }
      }
#pragma unroll
      for (int mt = 0; mt < 4; ++mt)
#pragma unroll
        for (int nt = 0; nt < 2; ++nt) {
          int col = n0 + nt * 16 + lr;
          float bias = A.b_fc[col];
#pragma unroll
          for (int r = 0; r < 4; ++r) {
            int row = mt * 16 + quad * 4 + r;
            int active = t < dls[row];
            nt_st_f32(&A.out_pred[((size_t)row * TSTEPS + t) * VDIM + col],
                      active ? (acc[mt][nt][r] + bias) : 0.f);
          }
        }
      __syncthreads();
    }
  }
}

// ---------------------------------------------------------------------------
extern "C" void kernel_launch(void* const* d_in, const int* in_sizes, int n_in,
                              void* d_out, int out_size, void* d_ws,
                              size_t ws_size, hipStream_t stream) {
  const float* encoder_out = (const float*)d_in[0];
  const int* encoded_captions = (const int*)d_in[1];
  const int* cap_len = (const int*)d_in[2];
  const float* W_enc = (const float*)d_in[3];
  const float* b_enc = (const float*)d_in[4];
  const float* W_dec = (const float*)d_in[5];
  const float* b_dec = (const float*)d_in[6];
  const float* w_full = (const float*)d_in[7];
  // d_in[8] = b_full (scalar; softmax-invariant, omitted)
  const float* emb_table = (const float*)d_in[9];
  const float* W_ih = (const float*)d_in[10];
  const float* W_hh = (const float*)d_in[11];
  const float* b_ih = (const float*)d_in[12];
  const float* b_hh = (const float*)d_in[13];
  const float* W_init_h = (const float*)d_in[14];
  const float* b_init_h = (const float*)d_in[15];
  const float* W_init_c = (const float*)d_in[16];
  const float* b_init_c = (const float*)d_in[17];
  const float* W_f_beta = (const float*)d_in[18];
  const float* b_f_beta = (const float*)d_in[19];
  const float* W_fc = (const float*)d_in[20];
  const float* b_fc = (const float*)d_in[21];

  float* out = (float*)d_out;
  float* out_pred = out;
  float* out_caps = out_pred + (size_t)BB * TSTEPS * VDIM;
  float* out_declen = out_caps + BB * MAXLEN;
  float* out_alphas = out_declen + BB;
  float* out_order = out_alphas + (size_t)BB * TSTEPS * PP;

  char* base = (char*)d_ws;
  ushort* Wfcb = (ushort*)(base + OFF_WFCB);
  ushort* Wcatb = (ushort*)(base + OFF_WCATB);
  ushort* Wdgb = (ushort*)(base + OFF_WDGB);
  ushort* Wencb = (ushort*)(base + OFF_WENCB);
  ushort* encb = (ushort*)(base + OFF_ENCB);
  ushort* eab = (ushort*)(base + OFF_EAB);
  float* WihT = (float*)(base + OFF_WIHT);
  float* WicT = (float*)(base + OFF_WICT);
  float* meanb = (float*)(base + OFF_MEAN);
  float* c0 = (float*)(base + OFF_C0);
  ushort* hbt = (ushort*)(base + OFF_HBT);
  float* dag = (float*)(base + OFF_DAG);
  ushort* xct = (ushort*)(base + OFF_XCT);
  int* order_i = (int*)(base + OFF_ORDER);
  int* declen_i = (int*)(base + OFF_DECLEN);
  unsigned* bar = (unsigned*)(base + OFF_BAR);

  dim3 tb(32, 8);
  k_sort<<<1, 64, 0, stream>>>(cap_len, encoded_captions, out_caps, out_declen,
                               out_order, order_i, declen_i, bar);
  // weight conversions (one-time per call)
  k_cvt<<<2048, 256, 0, stream>>>(W_fc, Wfcb, 16384000 / 4);
  k_cvt<<<64, 256, 0, stream>>>(W_enc, Wencb, 262144 / 4);
  k_cvt_cat<<<2048, 384, 0, stream>>>(W_ih, W_hh, Wcatb);
  k_cvt_dg<<<1024, 128, 0, stream>>>(W_dec, W_f_beta, Wdgb);
  k_encb<<<dim3(98, 64), 256, 0, stream>>>(encoder_out, order_i, encb);
  k_transpose<<<dim3(16, 16), tb, 0, stream>>>(W_init_h, 512, 512, WihT, 512);
  k_transpose<<<dim3(16, 16), tb, 0, stream>>>(W_init_c, 512, 512, WicT, 512);
  // prologue compute
  k_mean<<<64, 256, 0, stream>>>(encoder_out, order_i, meanb);
  k_init_hc<<<64, 256, 0, stream>>>(meanb, WihT, b_init_h, WicT, b_init_c,
                                    hbt, c0);
  k_ea_mfma<<<dim3(4, 196), 256, 0, stream>>>(encb, Wencb, b_enc, eab);

  // persistent decode + overlapped chunk-owned fc (cooperative launch)
  DecodeArgs hargs;
  hargs.Wdgb = Wdgb; hargs.b_dec = b_dec; hargs.b_fb = b_f_beta;
  hargs.eab = eab; hargs.w_full = w_full; hargs.encb = encb;
  hargs.emb_table = emb_table; hargs.caps = encoded_captions;
  hargs.order_i = order_i; hargs.declen_i = declen_i;
  hargs.Wcatb = Wcatb; hargs.b_ih = b_ih; hargs.b_hh = b_hh;
  hargs.c0 = c0; hargs.Wfcb = Wfcb; hargs.b_fc = b_fc;
  hargs.hbt = hbt; hargs.dag = dag; hargs.xct = xct;
  hargs.out_alphas = out_alphas; hargs.out_pred = out_pred;
  hargs.cnt = bar; hargs.flag = bar + 16;
  void* kargs[] = { (void*)&hargs };
  hipLaunchCooperativeKernel((const void*)k_decode_loop, dim3(GRID_TOTAL),
                             dim3(512), kargs, 0, stream);
}

// Round 7
// 3113.034 us; speedup vs baseline: 3.3767x; 1.2944x over previous
//
#include <hip/hip_runtime.h>
#include <hip/hip_bf16.h>
#include <math.h>

// Problem constants
#define BB      64
#define PP      196      // 14*14
#define ENCD    512
#define ADIM    512
#define DDIM    512
#define EDIM    512
#define VDIM    32000
#define MAXLEN  51
#define TSTEPS  50       // MAXLEN - 1
#define KCAT    1536     // E + ENC + D
#define GDIM    2048     // 4*D

#define NDECODE 64        // decode blocks (barrier participants)
#define NFC     125       // fc blocks: one per 256-col W_fc chunk
#define GRID_TOTAL (NDECODE + NFC)

typedef __attribute__((ext_vector_type(8))) short bf16x8;
typedef __attribute__((ext_vector_type(4))) float f32x4;

__device__ __forceinline__ ushort f2b(float x) {
  __hip_bfloat16 h = __float2bfloat16(x);
  return *reinterpret_cast<ushort*>(&h);
}
__device__ __forceinline__ float b2f(ushort u) {
  unsigned v = ((unsigned)u) << 16;
  return __uint_as_float(v);
}

// Cross-XCD write-through stores: visible at L3 without cache maintenance.
// Readers use NORMAL loads of t-indexed fresh addresses (first touch misses
// local L2 -> L3 has the data). No acquire fences => weights stay L2-resident.
__device__ __forceinline__ void st_wt_f32(float* p, float v) {
  __hip_atomic_store(p, v, __ATOMIC_RELAXED, __HIP_MEMORY_SCOPE_AGENT);
}
__device__ __forceinline__ void st_wt_u16(ushort* p, ushort v) {
  __hip_atomic_store(p, v, __ATOMIC_RELAXED, __HIP_MEMORY_SCOPE_AGENT);
}

// ---------------------------------------------------------------------------
// Workspace layout (byte offsets), total ~95 MB.
#define OFF_WFCB   0ull            // 32,768,000  bf16 W_fc (32000x512)
#define OFF_WCATB  32768000ull     //  6,291,456  bf16 [W_ih|W_hh] (2048x1536)
#define OFF_WDGB   39059456ull     //  1,048,576  bf16 [W_dec;W_f_beta] (1024x512)
#define OFF_WENCB  40108032ull     //    524,288  bf16 W_enc (512x512)
#define OFF_ENCB   40632320ull     // 12,845,056  bf16 enc sorted (64x196x512)
#define OFF_EAB    53477376ull     // 12,845,056  bf16 ea (64x196x512)
#define OFF_WIHT   66322432ull     //  1,048,576  f32 W_init_h^T
#define OFF_WICT   67371008ull     //  1,048,576  f32 W_init_c^T
#define OFF_MEAN   68419584ull     //    131,072  f32 mean_enc
#define OFF_C0     68550656ull     //    131,072  f32 c0
#define OFF_HBT    68681728ull     //  3,342,336  bf16 h history [51][64][512]
#define OFF_DAG    72024064ull     // 13,107,200  f32 [50][64][1024] da|gate
#define OFF_XCT    85131264ull     //  9,830,400  bf16 [50][64][1536] xcat
#define OFF_ORDER  94961664ull
#define OFF_DECLEN 94961920ull
#define OFF_BAR    94962176ull     // barrier: grp cnts @ [g*16], master @ [128],
                                   // flag @ [144]

// ---------------------------------------------------------------------------
__global__ __launch_bounds__(64) void k_sort(
    const int* __restrict__ cap_len, const int* __restrict__ caps,
    float* __restrict__ out_caps, float* __restrict__ out_declen,
    float* __restrict__ out_order, int* __restrict__ order_i,
    int* __restrict__ declen_i, unsigned* __restrict__ bar) {
  __shared__ int lens[BB];
  __shared__ int ord[BB];
  int i = threadIdx.x;
  for (int j = i; j < 256; j += 64) bar[j] = 0u;  // zero barrier region
  lens[i] = cap_len[i];
  __syncthreads();
  int li = lens[i];
  int rank = 0;
  for (int j = 0; j < BB; ++j) {
    int lj = lens[j];
    if (lj > li || (lj == li && j < i)) rank++;
  }
  ord[rank] = i;
  __syncthreads();
  int ob = ord[i];
  order_i[i] = ob;
  int dl = lens[ob] - 1;
  declen_i[i] = dl;
  out_declen[i] = (float)dl;
  out_order[i] = (float)ob;
  for (int j = 0; j < MAXLEN; ++j)
    out_caps[i * MAXLEN + j] = (float)caps[ob * MAXLEN + j];
}

// ---------------------------------------------------------------------------
__global__ __launch_bounds__(256) void k_cvt(
    const float* __restrict__ src, ushort* __restrict__ dst, int n4) {
  for (int i = blockIdx.x * 256 + threadIdx.x; i < n4; i += gridDim.x * 256) {
    float4 v = *(const float4*)(src + 4 * (size_t)i);
    ushort4 o;
    o.x = f2b(v.x); o.y = f2b(v.y); o.z = f2b(v.z); o.w = f2b(v.w);
    *(ushort4*)(dst + 4 * (size_t)i) = o;
  }
}

__global__ __launch_bounds__(384) void k_cvt_cat(
    const float* __restrict__ W_ih, const float* __restrict__ W_hh,
    ushort* __restrict__ dst) {
  int n = blockIdx.x;
  int k = threadIdx.x * 4;
  const float* src = (k < 1024) ? (W_ih + (size_t)n * 1024 + k)
                                : (W_hh + (size_t)n * 512 + (k - 1024));
  float4 v = *(const float4*)src;
  ushort4 o;
  o.x = f2b(v.x); o.y = f2b(v.y); o.z = f2b(v.z); o.w = f2b(v.w);
  *(ushort4*)(dst + (size_t)n * KCAT + k) = o;
}

__global__ __launch_bounds__(128) void k_cvt_dg(
    const float* __restrict__ W_dec, const float* __restrict__ W_fb,
    ushort* __restrict__ dst) {
  int n = blockIdx.x;
  int k = threadIdx.x * 4;
  const float* src = (n < 512) ? (W_dec + (size_t)n * 512 + k)
                               : (W_fb + (size_t)(n - 512) * 512 + k);
  float4 v = *(const float4*)src;
  ushort4 o;
  o.x = f2b(v.x); o.y = f2b(v.y); o.z = f2b(v.z); o.w = f2b(v.w);
  *(ushort4*)(dst + (size_t)n * 512 + k) = o;
}

__global__ __launch_bounds__(256) void k_encb(
    const float* __restrict__ enc, const int* __restrict__ order_i,
    ushort* __restrict__ encb) {
  int b = blockIdx.y;
  int ob = order_i[b];
  int off = blockIdx.x * 1024 + threadIdx.x * 4;
  float4 v = *(const float4*)(enc + (size_t)ob * (PP * ENCD) + off);
  ushort4 o;
  o.x = f2b(v.x); o.y = f2b(v.y); o.z = f2b(v.z); o.w = f2b(v.w);
  *(ushort4*)(encb + (size_t)b * (PP * ENCD) + off) = o;
}

// ---------------------------------------------------------------------------
__global__ __launch_bounds__(256) void k_transpose(
    const float* __restrict__ src, int R, int C,
    float* __restrict__ dst, int dstLD) {
  __shared__ float tile[32][33];
  int tx = threadIdx.x, ty = threadIdx.y;   // 32 x 8
  int c0 = blockIdx.x * 32, r0 = blockIdx.y * 32;
  for (int i = ty; i < 32; i += 8)
    tile[i][tx] = src[(size_t)(r0 + i) * C + (c0 + tx)];
  __syncthreads();
  for (int i = ty; i < 32; i += 8)
    dst[(size_t)(c0 + i) * dstLD + (r0 + tx)] = tile[tx][i];
}

// ---------------------------------------------------------------------------
__global__ __launch_bounds__(256) void k_mean(
    const float* __restrict__ enc, const int* __restrict__ order_i,
    float* __restrict__ mean_enc) {
  int b = blockIdx.x;
  int ob = order_i[b];
  const float* src = enc + (size_t)ob * PP * ENCD;
  for (int e = threadIdx.x; e < ENCD; e += 256) {
    float acc = 0.f;
    for (int p = 0; p < PP; ++p) acc += src[p * ENCD + e];
    mean_enc[b * ENCD + e] = acc * (1.f / PP);
  }
}

// ---------------------------------------------------------------------------
__global__ __launch_bounds__(256) void k_init_hc(
    const float* __restrict__ mean_enc, const float* __restrict__ WhT,
    const float* __restrict__ bh, const float* __restrict__ WcT,
    const float* __restrict__ bc, ushort* __restrict__ hbt0,
    float* __restrict__ c0) {
  __shared__ float m[ENCD];
  int b = blockIdx.x;
  for (int k = threadIdx.x; k < ENCD; k += 256) m[k] = mean_enc[b * ENCD + k];
  __syncthreads();
  for (int d = threadIdx.x; d < DDIM; d += 256) {
    float ah = bh[d], ac = bc[d];
    for (int k = 0; k < ENCD; ++k) {
      float mv = m[k];
      ah += mv * WhT[k * DDIM + d];
      ac += mv * WcT[k * DDIM + d];
    }
    hbt0[b * DDIM + d] = f2b(ah);
    c0[b * DDIM + d] = ac;
  }
}

// ---------------------------------------------------------------------------
// MFMA GEMM: ea = encb @ W_enc^T + b_enc -> bf16 eab. M=12544, N=512, K=512.
__global__ __launch_bounds__(256) void k_ea_mfma(
    const ushort* __restrict__ encb, const ushort* __restrict__ Wencb,
    const float* __restrict__ b_enc, ushort* __restrict__ eab) {
  int tid = threadIdx.x, wave = tid >> 6, lane = tid & 63;
  int quad = lane >> 4, lr = lane & 15;
  int m0 = blockIdx.y * 64;
  int n0 = blockIdx.x * 128 + wave * 32;
  const ushort* Arow = encb + ((size_t)(m0 + lr)) * 512 + quad * 8;
  const ushort* B0 = Wencb + (size_t)(n0 + lr) * 512 + quad * 8;
  const ushort* B1 = B0 + 16 * 512;
  f32x4 acc[4][2] = {};
  for (int k0 = 0; k0 < 512; k0 += 32) {
    bf16x8 b0 = *reinterpret_cast<const bf16x8*>(B0 + k0);
    bf16x8 b1 = *reinterpret_cast<const bf16x8*>(B1 + k0);
#pragma unroll
    for (int mt = 0; mt < 4; ++mt) {
      bf16x8 a = *reinterpret_cast<const bf16x8*>(Arow + mt * 16 * 512 + k0);
      acc[mt][0] = __builtin_amdgcn_mfma_f32_16x16x32_bf16(a, b0, acc[mt][0], 0, 0, 0);
      acc[mt][1] = __builtin_amdgcn_mfma_f32_16x16x32_bf16(a, b1, acc[mt][1], 0, 0, 0);
    }
  }
#pragma unroll
  for (int mt = 0; mt < 4; ++mt)
#pragma unroll
    for (int nt = 0; nt < 2; ++nt) {
      int col = n0 + nt * 16 + lr;
      float bias = b_enc[col];
#pragma unroll
      for (int r = 0; r < 4; ++r) {
        int row = m0 + mt * 16 + quad * 4 + r;
        eab[(size_t)row * 512 + col] = f2b(acc[mt][nt][r] + bias);
      }
    }
}

// ---------------------------------------------------------------------------
// Two-level grid barrier among NDECODE blocks: relaxed agent atomics only —
// no cache invalidation (weights stay L2-resident). 8 groups x 8 blocks on
// separate cache lines, monotonic counters.
__device__ __forceinline__ void lsync(unsigned* bar, unsigned& gen) {
  __syncthreads();
  if (threadIdx.x == 0) {
    ++gen;
    asm volatile("s_waitcnt vmcnt(0)" ::: "memory");
    unsigned g = blockIdx.x & 7u;
    unsigned old = __hip_atomic_fetch_add(bar + g * 16, 1u, __ATOMIC_RELAXED,
                                          __HIP_MEMORY_SCOPE_AGENT);
    if (old == gen * 8u - 1u) {
      unsigned m = __hip_atomic_fetch_add(bar + 128, 1u, __ATOMIC_RELAXED,
                                          __HIP_MEMORY_SCOPE_AGENT);
      if (m == gen * 8u - 1u)
        __hip_atomic_store(bar + 144, gen, __ATOMIC_RELAXED,
                           __HIP_MEMORY_SCOPE_AGENT);
    }
    while (__hip_atomic_load(bar + 144, __ATOMIC_RELAXED,
                             __HIP_MEMORY_SCOPE_AGENT) < gen)
      __builtin_amdgcn_s_sleep(1);
  }
  __syncthreads();
}

// ---------------------------------------------------------------------------
struct DecodeArgs {
  const ushort* Wdgb;
  const float* b_dec;
  const float* b_fb;
  const ushort* eab;
  const float* w_full;
  const ushort* encb;
  const float* emb_table;
  const int* caps;
  const int* order_i;
  const int* declen_i;
  const ushort* Wcatb;
  const float* b_ih;
  const float* b_hh;
  const float* c0;
  const ushort* Wfcb;
  const float* b_fc;
  ushort* hbt;        // [51][64][512] h history (write-through)
  float* dag;         // [50][64][1024] da|gate (write-through)
  ushort* xct;        // [50][64][1536] xcat (write-through)
  float* out_alphas;
  float* out_pred;
  unsigned* bar;
};

// ---------------------------------------------------------------------------
// Persistent kernel: 189 blocks x 1024 threads (16 waves), cooperative launch.
// Blocks 0..63  : decode loop, 3 lsync barriers/step.
//   P1: dagate, 64 blocks x 16 cols, 4 m-tiles x 4 K-quarters  -> dag[t]
//   P2: attention, block b = batch b, 16 waves                  -> xcat[t]
//   P3: gates GEMM 4g x 2mq x 2kh split-K + fused LSTM          -> hbt[t+1]
// Blocks 64..188: fc chunk-owned (256 cols, 16 waves x 16 cols), cached W_fc,
//   gated on flag >= 3*(t+1).
// LDS: shbuf (32 KB) is time-multiplexed between ctxp[16][512] (P2 ctx
// reduce) and sg[4][4][32][16] (P1/P3 split-K partials) — phases are
// barrier-separated and each fully overwrites what it reads.
__global__ __launch_bounds__(1024) void k_decode_loop(DecodeArgs A) {
  __shared__ int dls[BB];
  __shared__ float wf[ADIM];
  __shared__ float das[ADIM];
  __shared__ float sc[PP];
  __shared__ float shbuf[8192];   // 32 KB aliased scratch
  typedef float (*ctxp_t)[512];          // [16][512]
  typedef float (*sg_t)[4][32][16];      // [4][4][32][16]
  ctxp_t ctxp = (ctxp_t)shbuf;
  sg_t sg = (sg_t)shbuf;
  int tid = threadIdx.x;
  int bid = blockIdx.x;
  int wave = tid >> 6, lane = tid & 63;
  int quad = lane >> 4, lr = lane & 15;

  if (tid < BB) dls[tid] = A.declen_i[tid];
  __syncthreads();

  if (bid < NDECODE) {
    // =========================== decode path ==============================
    if (tid < ADIM) wf[tid] = A.w_full[tid];
    __syncthreads();
    unsigned gen = 0;
    float creg = 0.f;   // P3 cell state (tid<512): this thread's (row,d)
    int b = bid;
    // P3 geometry: 32 col-groups x 2 m-halves
    int d0 = (bid >> 1) * 16;
    int mh = bid & 1;
    int g3 = wave & 3, mq = (wave >> 2) & 1, khh = wave >> 3;
    // P1 geometry: 64 blocks x 16 cols; wave = (mt, kq)
    int p1n0 = bid * 16;
    int p1mt = wave & 3, p1kq = wave >> 2;   // 4 m-tiles x 4 K-quarters

    for (int t = 0; t < TSTEPS; ++t) {
      const ushort* hcur = A.hbt + (size_t)t * BB * DDIM;
      float* dagt = A.dag + (size_t)t * BB * 1024;
      ushort* xctt = A.xct + (size_t)t * BB * KCAT;

      // ---- P1: [da | gate] = h_t @ [W_dec;W_f_beta]^T ----
      {
        const ushort* Arow = hcur + (size_t)(p1mt * 16 + lr) * 512 + quad * 8;
        const ushort* Bp = A.Wdgb + (size_t)(p1n0 + lr) * 512 + quad * 8;
        f32x4 acc = {};
        int kbase = p1kq * 128;
#pragma unroll
        for (int k0 = 0; k0 < 128; k0 += 32) {
          bf16x8 bfr = *reinterpret_cast<const bf16x8*>(Bp + kbase + k0);
          bf16x8 a = *reinterpret_cast<const bf16x8*>(Arow + kbase + k0);
          acc = __builtin_amdgcn_mfma_f32_16x16x32_bf16(a, bfr, acc, 0, 0, 0);
        }
#pragma unroll
        for (int r = 0; r < 4; ++r)
          sg[p1kq][p1mt][quad * 4 + r][lr] = acc[r];
        __syncthreads();
        int row = tid >> 4, dd = tid & 15;
        int mt = row >> 4, r16 = row & 15;
        float v = sg[0][mt][r16][dd] + sg[1][mt][r16][dd] +
                  sg[2][mt][r16][dd] + sg[3][mt][r16][dd];
        int col = p1n0 + dd;
        if (col < 512) {
          st_wt_f32(&dagt[row * 1024 + col], v + A.b_dec[col]);
        } else {
          int cg = col - 512;
          st_wt_f32(&dagt[row * 1024 + col],
                    1.f / (1.f + expf(-(v + A.b_fb[cg]))));
        }
      }
      lsync(A.bar, gen);

      // ---- P2: attention (block b = batch b, 16 waves) ----
      {
        if (tid < ADIM) das[tid] = dagt[b * 1024 + tid];
        int tok = A.caps[A.order_i[b] * MAXLEN + t];
        if (tid < 512) {
          st_wt_u16(&xctt[(size_t)b * KCAT + tid],
                    f2b(A.emb_table[(size_t)tok * EDIM + tid]));
          st_wt_u16(&xctt[(size_t)b * KCAT + 1024 + tid], hcur[b * 512 + tid]);
        }
        __syncthreads();
        // scores over p, 16 waves
#pragma unroll 2
        for (int p = wave; p < PP; p += 16) {
          const ushort* ep = A.eab + ((size_t)b * PP + p) * ADIM + lane * 8;
          bf16x8 ev = *reinterpret_cast<const bf16x8*>(ep);
          float s = 0.f;
#pragma unroll
          for (int j = 0; j < 8; ++j) {
            int a = lane * 8 + j;
            float e = b2f((ushort)ev[j]);
            s += fmaxf(e + das[a], 0.f) * wf[a];
          }
#pragma unroll
          for (int off = 32; off; off >>= 1) s += __shfl_xor(s, off);
          if (lane == 0) sc[p] = s;
        }
        __syncthreads();
        if (wave == 0) {  // softmax over 196
          float m = -1e30f;
          for (int p = lane; p < PP; p += 64) m = fmaxf(m, sc[p]);
#pragma unroll
          for (int off = 32; off; off >>= 1) m = fmaxf(m, __shfl_xor(m, off));
          float ssum = 0.f;
          for (int p = lane; p < PP; p += 64) {
            float e = expf(sc[p] - m);
            sc[p] = e;
            ssum += e;
          }
#pragma unroll
          for (int off = 32; off; off >>= 1) ssum += __shfl_xor(ssum, off);
          float inv = 1.f / ssum;
          for (int p = lane; p < PP; p += 64) sc[p] *= inv;
        }
        __syncthreads();
        int active = t < dls[b];
        if (tid < PP)
          A.out_alphas[((size_t)b * TSTEPS + t) * PP + tid] =
              active ? sc[tid] : 0.f;
        // ctx: thread = (e-group of 8, p-group of 16); 16B loads, LDS reduce
        int e8 = tid & 63, pg = tid >> 6;
        float a8[8] = {0.f, 0.f, 0.f, 0.f, 0.f, 0.f, 0.f, 0.f};
        const ushort* eb = A.encb + (size_t)b * (PP * ENCD) + e8 * 8;
#pragma unroll 2
        for (int p = pg; p < PP; p += 16) {
          float al = sc[p];
          bf16x8 ev = *reinterpret_cast<const bf16x8*>(eb + (size_t)p * ENCD);
#pragma unroll
          for (int j = 0; j < 8; ++j) a8[j] += al * b2f((ushort)ev[j]);
        }
#pragma unroll
        for (int j = 0; j < 8; ++j) ctxp[pg][e8 * 8 + j] = a8[j];
        __syncthreads();
        if (tid < 512) {
          float cx = 0.f;
#pragma unroll
          for (int g = 0; g < 16; ++g) cx += ctxp[g][tid];
          cx *= dagt[b * 1024 + 512 + tid];
          st_wt_u16(&xctt[(size_t)b * KCAT + 512 + tid], f2b(cx));
        }
        __syncthreads();
      }
      lsync(A.bar, gen);

      // ---- P3: gates GEMM (split-K 2-way) + fused LSTM ----
      {
        int mt = mh * 2 + mq;
        int colbase = g3 * 512 + d0;
        const ushort* Arow = xctt + (size_t)(mt * 16 + lr) * KCAT + quad * 8;
        const ushort* Bp = A.Wcatb + (size_t)(colbase + lr) * KCAT + quad * 8;
        f32x4 acc = {};
        int kb = khh * 768;
        for (int k0 = 0; k0 < 768; k0 += 32) {
          bf16x8 bfr = *reinterpret_cast<const bf16x8*>(Bp + kb + k0);
          bf16x8 a = *reinterpret_cast<const bf16x8*>(Arow + kb + k0);
          acc = __builtin_amdgcn_mfma_f32_16x16x32_bf16(a, bfr, acc, 0, 0, 0);
        }
#pragma unroll
        for (int r = 0; r < 4; ++r)
          sg[khh][g3][mq * 16 + quad * 4 + r][lr] = acc[r];
        __syncthreads();
        if (tid < 512) {
          ushort* hnext = A.hbt + (size_t)(t + 1) * BB * DDIM;
          int rowl = tid >> 4, dd = tid & 15;
          int row = mh * 32 + rowl;
          int d = d0 + dd;
          float gi = sg[0][0][rowl][dd] + sg[1][0][rowl][dd] + A.b_ih[d] + A.b_hh[d];
          float gf = sg[0][1][rowl][dd] + sg[1][1][rowl][dd] + A.b_ih[512 + d] + A.b_hh[512 + d];
          float gg = sg[0][2][rowl][dd] + sg[1][2][rowl][dd] + A.b_ih[1024 + d] + A.b_hh[1024 + d];
          float go = sg[0][3][rowl][dd] + sg[1][3][rowl][dd] + A.b_ih[1536 + d] + A.b_hh[1536 + d];
          float si = 1.f / (1.f + expf(-gi));
          float sf = 1.f / (1.f + expf(-gf));
          float so = 1.f / (1.f + expf(-go));
          if (t == 0) creg = A.c0[row * DDIM + d];
          float cn = sf * creg + si * tanhf(gg);
          creg = cn;
          float hn = so * tanhf(cn);
          st_wt_u16(&hnext[row * DDIM + d], f2b(hn));
        }
        __syncthreads();
      }
      lsync(A.bar, gen);
    }
  } else {
    // ============================ fc path =================================
    // Block owns a 256-col W_fc chunk; 16 waves x 16 cols; cached B loads
    // (chunk-owned -> L2 reuse across t); gated on flag >= 3*(t+1).
    int chunk = bid - NDECODE;   // 0..124
    int n0 = chunk * 256 + wave * 16;
    const ushort* B0 = A.Wfcb + (size_t)(n0 + lr) * 512 + quad * 8;
    for (int t = 0; t < TSTEPS; ++t) {
      if (tid == 0) {
        unsigned need = 3u * (unsigned)(t + 1);
        while (__hip_atomic_load(A.bar + 144, __ATOMIC_RELAXED,
                                 __HIP_MEMORY_SCOPE_AGENT) < need)
          __builtin_amdgcn_s_sleep(16);
      }
      __syncthreads();
      const ushort* Arow = A.hbt + (size_t)(t + 1) * BB * DDIM +
                           (size_t)lr * 512 + quad * 8;
      f32x4 acc[4] = {};
      for (int k0 = 0; k0 < 512; k0 += 32) {
        bf16x8 b0 = *reinterpret_cast<const bf16x8*>(B0 + k0);
#pragma unroll
        for (int mt = 0; mt < 4; ++mt) {
          bf16x8 a = *reinterpret_cast<const bf16x8*>(Arow + mt * 16 * 512 + k0);
          acc[mt] = __builtin_amdgcn_mfma_f32_16x16x32_bf16(a, b0, acc[mt], 0, 0, 0);
        }
      }
      int col = n0 + lr;
      float bias = A.b_fc[col];
#pragma unroll
      for (int mt = 0; mt < 4; ++mt) {
#pragma unroll
        for (int r = 0; r < 4; ++r) {
          int row = mt * 16 + quad * 4 + r;
          int active = t < dls[row];
          A.out_pred[((size_t)row * TSTEPS + t) * VDIM + col] =
              active ? (acc[mt][r] + bias) : 0.f;
        }
      }
      __syncthreads();
    }
  }
}

// ---------------------------------------------------------------------------
extern "C" void kernel_launch(void* const* d_in, const int* in_sizes, int n_in,
                              void* d_out, int out_size, void* d_ws,
                              size_t ws_size, hipStream_t stream) {
  const float* encoder_out = (const float*)d_in[0];
  const int* encoded_captions = (const int*)d_in[1];
  const int* cap_len = (const int*)d_in[2];
  const float* W_enc = (const float*)d_in[3];
  const float* b_enc = (const float*)d_in[4];
  const float* W_dec = (const float*)d_in[5];
  const float* b_dec = (const float*)d_in[6];
  const float* w_full = (const float*)d_in[7];
  // d_in[8] = b_full (scalar; softmax-invariant, omitted)
  const float* emb_table = (const float*)d_in[9];
  const float* W_ih = (const float*)d_in[10];
  const float* W_hh = (const float*)d_in[11];
  const float* b_ih = (const float*)d_in[12];
  const float* b_hh = (const float*)d_in[13];
  const float* W_init_h = (const float*)d_in[14];
  const float* b_init_h = (const float*)d_in[15];
  const float* W_init_c = (const float*)d_in[16];
  const float* b_init_c = (const float*)d_in[17];
  const float* W_f_beta = (const float*)d_in[18];
  const float* b_f_beta = (const float*)d_in[19];
  const float* W_fc = (const float*)d_in[20];
  const float* b_fc = (const float*)d_in[21];

  float* out = (float*)d_out;
  float* out_pred = out;
  float* out_caps = out_pred + (size_t)BB * TSTEPS * VDIM;
  float* out_declen = out_caps + BB * MAXLEN;
  float* out_alphas = out_declen + BB;
  float* out_order = out_alphas + (size_t)BB * TSTEPS * PP;

  char* base = (char*)d_ws;
  ushort* Wfcb = (ushort*)(base + OFF_WFCB);
  ushort* Wcatb = (ushort*)(base + OFF_WCATB);
  ushort* Wdgb = (ushort*)(base + OFF_WDGB);
  ushort* Wencb = (ushort*)(base + OFF_WENCB);
  ushort* encb = (ushort*)(base + OFF_ENCB);
  ushort* eab = (ushort*)(base + OFF_EAB);
  float* WihT = (float*)(base + OFF_WIHT);
  float* WicT = (float*)(base + OFF_WICT);
  float* meanb = (float*)(base + OFF_MEAN);
  float* c0 = (float*)(base + OFF_C0);
  ushort* hbt = (ushort*)(base + OFF_HBT);
  float* dag = (float*)(base + OFF_DAG);
  ushort* xct = (ushort*)(base + OFF_XCT);
  int* order_i = (int*)(base + OFF_ORDER);
  int* declen_i = (int*)(base + OFF_DECLEN);
  unsigned* bar = (unsigned*)(base + OFF_BAR);

  dim3 tb(32, 8);
  k_sort<<<1, 64, 0, stream>>>(cap_len, encoded_captions, out_caps, out_declen,
                               out_order, order_i, declen_i, bar);
  // weight conversions (one-time per call)
  k_cvt<<<2048, 256, 0, stream>>>(W_fc, Wfcb, 16384000 / 4);
  k_cvt<<<64, 256, 0, stream>>>(W_enc, Wencb, 262144 / 4);
  k_cvt_cat<<<2048, 384, 0, stream>>>(W_ih, W_hh, Wcatb);
  k_cvt_dg<<<1024, 128, 0, stream>>>(W_dec, W_f_beta, Wdgb);
  k_encb<<<dim3(98, 64), 256, 0, stream>>>(encoder_out, order_i, encb);
  k_transpose<<<dim3(16, 16), tb, 0, stream>>>(W_init_h, 512, 512, WihT, 512);
  k_transpose<<<dim3(16, 16), tb, 0, stream>>>(W_init_c, 512, 512, WicT, 512);
  // prologue compute
  k_mean<<<64, 256, 0, stream>>>(encoder_out, order_i, meanb);
  k_init_hc<<<64, 256, 0, stream>>>(meanb, WihT, b_init_h, WicT, b_init_c,
                                    hbt, c0);
  k_ea_mfma<<<dim3(4, 196), 256, 0, stream>>>(encb, Wencb, b_enc, eab);

  // persistent decode + overlapped chunk-owned fc (cooperative launch)
  DecodeArgs hargs;
  hargs.Wdgb = Wdgb; hargs.b_dec = b_dec; hargs.b_fb = b_f_beta;
  hargs.eab = eab; hargs.w_full = w_full; hargs.encb = encb;
  hargs.emb_table = emb_table; hargs.caps = encoded_captions;
  hargs.order_i = order_i; hargs.declen_i = declen_i;
  hargs.Wcatb = Wcatb; hargs.b_ih = b_ih; hargs.b_hh = b_hh;
  hargs.c0 = c0; hargs.Wfcb = Wfcb; hargs.b_fc = b_fc;
  hargs.hbt = hbt; hargs.dag = dag; hargs.xct = xct;
  hargs.out_alphas = out_alphas; hargs.out_pred = out_pred;
  hargs.bar = bar;
  void* kargs[] = { (void*)&hargs };
  hipLaunchCooperativeKernel((const void*)k_decode_loop, dim3(GRID_TOTAL),
                             dim3(1024), kargs, 0, stream);
}